// Round 1
// baseline (1007.206 us; speedup 1.0000x reference)
//
#include <hip/hip_runtime.h>
#include <hip/hip_bf16.h>

// ---------------- constants ----------------
constexpr int kB   = 2;
constexpr int kN   = 1024;   // sequence length
constexpr int kDM  = 512;    // d_model
constexpr int kDI  = 1024;   // d_inner
constexpr int kDS  = 16;     // d_state
constexpr int kDTR = 32;     // dt_rank

typedef __attribute__((ext_vector_type(8))) __bf16 bf16x8;
typedef __attribute__((ext_vector_type(4))) __bf16 bf16x4;
typedef __attribute__((ext_vector_type(4))) float  f32x4;

__device__ __forceinline__ float sigmoidf_(float x) { return 1.f / (1.f + __expf(-x)); }
__device__ __forceinline__ float sum4(float4 a) { return a.x + a.y + a.z + a.w; }
__device__ __forceinline__ float dot4(float4 a) { return a.x*a.x + a.y*a.y + a.z*a.z + a.w*a.w; }
__device__ __forceinline__ float4 nrm4(float4 x, float mu, float rs, float4 w, float4 b) {
    return make_float4((x.x-mu)*rs*w.x + b.x, (x.y-mu)*rs*w.y + b.y,
                       (x.z-mu)*rs*w.z + b.z, (x.w-mu)*rs*w.w + b.w);
}

// ---------------- layernorm + channel exchange ----------------
// one 64-lane wave per token row (handles both I1 and I2); 4 rows per block
__launch_bounds__(256)
__global__ void ln_exchange_k(const float* __restrict__ I1, const float* __restrict__ I2,
                              const float* __restrict__ w1, const float* __restrict__ b1,
                              const float* __restrict__ w2, const float* __restrict__ b2,
                              float* __restrict__ s1, float* __restrict__ s2)
{
    int row  = blockIdx.x * 4 + (threadIdx.x >> 6);   // 0..2047
    int lane = threadIdx.x & 63;
    const float4* p1 = reinterpret_cast<const float4*>(I1 + (size_t)row * kDM);
    const float4* p2 = reinterpret_cast<const float4*>(I2 + (size_t)row * kDM);
    float4 xa1 = p1[lane], xb1 = p1[lane + 64];
    float4 xa2 = p2[lane], xb2 = p2[lane + 64];
    float su1 = sum4(xa1) + sum4(xb1), sq1 = dot4(xa1) + dot4(xb1);
    float su2 = sum4(xa2) + sum4(xb2), sq2 = dot4(xa2) + dot4(xb2);
    #pragma unroll
    for (int m = 32; m; m >>= 1) {
        su1 += __shfl_xor(su1, m, 64); sq1 += __shfl_xor(sq1, m, 64);
        su2 += __shfl_xor(su2, m, 64); sq2 += __shfl_xor(sq2, m, 64);
    }
    float mu1 = su1 * (1.f / kDM), v1 = sq1 * (1.f / kDM) - mu1 * mu1;
    float mu2 = su2 * (1.f / kDM), v2 = sq2 * (1.f / kDM) - mu2 * mu2;
    float rs1 = rsqrtf(v1 + 1e-5f), rs2 = rsqrtf(v2 + 1e-5f);
    const float4* W1 = reinterpret_cast<const float4*>(w1);
    const float4* B1 = reinterpret_cast<const float4*>(b1);
    const float4* W2 = reinterpret_cast<const float4*>(w2);
    const float4* B2 = reinterpret_cast<const float4*>(b2);
    float4 w1a = W1[lane], w1b = W1[lane+64], b1a = B1[lane], b1b = B1[lane+64];
    float4 w2a = W2[lane], w2b = W2[lane+64], b2a = B2[lane], b2b = B2[lane+64];
    float4 n1a = nrm4(xa1, mu1, rs1, w1a, b1a), n1b = nrm4(xb1, mu1, rs1, w1b, b1b);
    float4 n2a = nrm4(xa2, mu2, rs2, w2a, b2a), n2b = nrm4(xb2, mu2, rs2, w2b, b2b);
    // channel c even -> swap (even = components .x/.z since c = lane*4 + comp, lane*4 even)
    float4 o1a = make_float4(n2a.x, n1a.y, n2a.z, n1a.w);
    float4 o2a = make_float4(n1a.x, n2a.y, n1a.z, n2a.w);
    float4 o1b = make_float4(n2b.x, n1b.y, n2b.z, n1b.w);
    float4 o2b = make_float4(n1b.x, n2b.y, n1b.z, n2b.w);
    float4* q1 = reinterpret_cast<float4*>(s1 + (size_t)row * kDM);
    float4* q2 = reinterpret_cast<float4*>(s2 + (size_t)row * kDM);
    q1[lane] = o1a; q1[lane + 64] = o1b;
    q2[lane] = o2a; q2[lane + 64] = o2b;
}

// ---------------- SE column sums (over N tokens) ----------------
// grid: 64 blocks = tensor(2) x b(2) x c-chunk(2) x n-chunk(8); 256 threads (one c each)
__launch_bounds__(256)
__global__ void col_sum_k(const float* __restrict__ s1, const float* __restrict__ s2,
                          float* __restrict__ sum1, float* __restrict__ sum2)
{
    int x = blockIdx.x;
    int t  = x & 1;
    int b  = (x >> 1) & 1;
    int cc = (x >> 2) & 1;
    int nc = x >> 3;                  // 0..7
    int c = cc * 256 + threadIdx.x;
    const float* src = (t ? s2 : s1) + (size_t)b * kN * kDM + (size_t)nc * 128 * kDM + c;
    float acc = 0.f;
    for (int n = 0; n < 128; ++n) acc += src[(size_t)n * kDM];
    atomicAdd((t ? sum2 : sum1) + b * kDM + c, acc);
}

// ---------------- SE MLP: scale = sigmoid(relu(mean@w1^T)@w2^T) ----------------
__launch_bounds__(128)
__global__ void se_mlp_k(const float* __restrict__ sum1, const float* __restrict__ sum2,
                         const float* __restrict__ w1, const float* __restrict__ w2,
                         float* __restrict__ scl1, float* __restrict__ scl2)
{
    int t = blockIdx.x >> 1, b = blockIdx.x & 1;
    const float* sums = (t ? sum2 : sum1) + b * kDM;
    float* scl = (t ? scl2 : scl1) + b * kDM;
    __shared__ float m[kDM];
    __shared__ float hid[128];
    for (int c = threadIdx.x; c < kDM; c += 128) m[c] = sums[c] * (1.f / kN);
    __syncthreads();
    int j = threadIdx.x;
    float acc = 0.f;
    for (int c = 0; c < kDM; ++c) acc = fmaf(m[c], w1[j * kDM + c], acc);
    hid[j] = fmaxf(acc, 0.f);
    __syncthreads();
    for (int c = j; c < kDM; c += 128) {
        float a2 = 0.f;
        for (int k = 0; k < 128; ++k) a2 = fmaf(hid[k], w2[c * 128 + k], a2);
        scl[c] = sigmoidf_(a2);
    }
}

// ---------------- scale by SE gate + convert to bf16 ----------------
__launch_bounds__(256)
__global__ void scale_cvt_k(const float* __restrict__ s, const float* __restrict__ scl,
                            __bf16* __restrict__ out)
{
    int idx = blockIdx.x * 256 + threadIdx.x;     // 262144 float4 groups
    float4 v = reinterpret_cast<const float4*>(s)[idx];
    int c4 = idx & 127;          // 128 float4 per row
    int row = idx >> 7;
    int b = row >> 10;
    float4 sc = reinterpret_cast<const float4*>(scl + b * kDM)[c4];
    bf16x4 o = { (__bf16)(v.x * sc.x), (__bf16)(v.y * sc.y),
                 (__bf16)(v.z * sc.z), (__bf16)(v.w * sc.w) };
    reinterpret_cast<bf16x4*>(out)[idx] = o;
}

// ---------------- f32 -> bf16 weight convert ----------------
__launch_bounds__(256)
__global__ void cvt_bf16_k(const float* __restrict__ src, __bf16* __restrict__ dst, int n4)
{
    int idx = blockIdx.x * 256 + threadIdx.x;
    if (idx >= n4) return;
    float4 v = reinterpret_cast<const float4*>(src)[idx];
    bf16x4 o = { (__bf16)v.x, (__bf16)v.y, (__bf16)v.z, (__bf16)v.w };
    reinterpret_cast<bf16x4*>(dst)[idx] = o;
}

// ---------------- bf16 MFMA GEMM:  C[M,N] = A[M,K] @ Bw[N,K]^T (+R) ----------------
// wave computes (16*WM16)x(16*WN16); LDS-free (operands are L2-resident here)
template<int WM16, int WN16, bool ADD_RES>
__global__ __launch_bounds__(256) void gemm_bt(
    const __bf16* __restrict__ A, const __bf16* __restrict__ Bw,
    const float* __restrict__ R, float* __restrict__ C,
    int M, int N, int K)
{
    constexpr int WM = 16 * WM16, WN = 16 * WN16;
    int wave = blockIdx.x * (blockDim.x >> 6) + (threadIdx.x >> 6);
    int tiles_n = N / WN;
    int tiles_m = M / WM;
    if (wave >= tiles_m * tiles_n) return;
    int tm = wave / tiles_n, tn = wave % tiles_n;
    int lane = threadIdx.x & 63;
    int r = lane & 15;
    int ko = (lane >> 4) * 8;
    const __bf16* Abase = A  + (size_t)(tm * WM + r) * K + ko;
    const __bf16* Bbase = Bw + (size_t)(tn * WN + r) * K + ko;
    f32x4 acc[WM16][WN16];
    #pragma unroll
    for (int i = 0; i < WM16; ++i)
        #pragma unroll
        for (int j = 0; j < WN16; ++j)
            acc[i][j] = (f32x4){0.f, 0.f, 0.f, 0.f};
    for (int k0 = 0; k0 < K; k0 += 32) {
        bf16x8 a[WM16], b[WN16];
        #pragma unroll
        for (int i = 0; i < WM16; ++i)
            a[i] = *reinterpret_cast<const bf16x8*>(Abase + (size_t)i * 16 * K + k0);
        #pragma unroll
        for (int j = 0; j < WN16; ++j)
            b[j] = *reinterpret_cast<const bf16x8*>(Bbase + (size_t)j * 16 * K + k0);
        #pragma unroll
        for (int i = 0; i < WM16; ++i)
            #pragma unroll
            for (int j = 0; j < WN16; ++j)
                acc[i][j] = __builtin_amdgcn_mfma_f32_16x16x32_bf16(a[i], b[j], acc[i][j], 0, 0, 0);
    }
    int row0 = tm * WM + ((lane >> 4) << 2);
    int col0 = tn * WN + (lane & 15);
    #pragma unroll
    for (int i = 0; i < WM16; ++i)
        #pragma unroll
        for (int j = 0; j < WN16; ++j)
            #pragma unroll
            for (int rr = 0; rr < 4; ++rr) {
                size_t idx = (size_t)(row0 + i * 16 + rr) * N + col0 + j * 16;
                float v = acc[i][j][rr];
                if (ADD_RES) v += R[idx];
                C[idx] = v;
            }
}

// ---------------- causal depthwise conv (width 4) + bias + SiLU ----------------
__launch_bounds__(256)
__global__ void conv_silu_k(const float* __restrict__ xz, const float* __restrict__ cw,
                            const float* __restrict__ cb,
                            float* __restrict__ xcf, __bf16* __restrict__ xcb)
{
    int idx = blockIdx.x * 256 + threadIdx.x;    // B*N*DI = 2M
    int d = idx & (kDI - 1);
    int n = (idx >> 10) & (kN - 1);
    int b = idx >> 20;
    const float* base = xz + (size_t)(b << 10) * (2 * kDI) + d;
    float acc = cb[d];
    #pragma unroll
    for (int j = 0; j < 4; ++j) {
        int nn = n - 3 + j;
        if (nn >= 0) acc = fmaf(base[(size_t)nn * (2 * kDI)], cw[d * 4 + j], acc);
    }
    float o = acc * sigmoidf_(acc);
    xcf[idx] = o;
    xcb[idx] = (__bf16)o;
}

// ---------------- dt = softplus(x_dbl[:, :32] @ dt_w^T + dt_b) ----------------
// grid: (32 m-chunks of 64 rows, 4 d-chunks of 256)
__launch_bounds__(256)
__global__ void dt_softplus_k(const float* __restrict__ xd, const float* __restrict__ dtw,
                              const float* __restrict__ dtb, float* __restrict__ dtout)
{
    int d = blockIdx.y * 256 + threadIdx.x;
    int m0 = blockIdx.x * 64;
    float w[kDTR];
    #pragma unroll
    for (int rr = 0; rr < kDTR; ++rr) w[rr] = dtw[d * kDTR + rr];
    float bias = dtb[d];
    for (int m = m0; m < m0 + 64; ++m) {
        const float* x = xd + (size_t)m * 64;
        float acc = bias;
        #pragma unroll
        for (int rr = 0; rr < kDTR; ++rr) acc = fmaf(x[rr], w[rr], acc);
        float sp = acc > 15.f ? acc : log1pf(__expf(acc));
        dtout[(size_t)m * kDI + d] = sp;
    }
}

// ---------------- selective scan (both mambas in one launch) ----------------
// 16 lanes per (b,d) channel, one state per lane; 128 blocks per mamba
__launch_bounds__(256)
__global__ void scan_k(const float* __restrict__ dt_0, const float* __restrict__ dt_1,
                       const float* __restrict__ xc_0, const float* __restrict__ xc_1,
                       const float* __restrict__ xz_0, const float* __restrict__ xz_1,
                       const float* __restrict__ xd_0, const float* __restrict__ xd_1,
                       const float* __restrict__ Al_0, const float* __restrict__ Al_1,
                       const float* __restrict__ Dp_0, const float* __restrict__ Dp_1,
                       __bf16* __restrict__ yg_0, __bf16* __restrict__ yg_1)
{
    int mam = blockIdx.x >> 7;
    const float* dtp = mam ? dt_1 : dt_0;
    const float* xcp = mam ? xc_1 : xc_0;
    const float* xzp = mam ? xz_1 : xz_0;
    const float* xdp = mam ? xd_1 : xd_0;
    const float* Alp = mam ? Al_1 : Al_0;
    const float* Dpp = mam ? Dp_1 : Dp_0;
    __bf16* ygp = mam ? yg_1 : yg_0;

    int p = ((blockIdx.x & 127) << 4) + (threadIdx.x >> 4);  // 0..2047
    int s = threadIdx.x & 15;
    int d = p & (kDI - 1), b = p >> 10;
    float a_s = -__expf(Alp[d * kDS + s]);
    float Dd = Dpp[d];
    float h = 0.f;
    const float* dtrow = dtp + (size_t)b * kN * kDI + d;
    const float* xcrow = xcp + (size_t)b * kN * kDI + d;
    const float* zrow  = xzp + (size_t)b * kN * 2 * kDI + kDI + d;
    const float* xdrow = xdp + (size_t)b * kN * 64;
    for (int t = 0; t < kN; ++t) {
        float dtv = dtrow[(size_t)t * kDI];
        float xcv = xcrow[(size_t)t * kDI];
        float zv  = zrow[(size_t)t * 2 * kDI];
        float Bv  = xdrow[t * 64 + 32 + s];
        float Cv  = xdrow[t * 64 + 48 + s];
        float dA  = __expf(dtv * a_s);
        h = fmaf(dA, h, dtv * Bv * xcv);
        float pc = h * Cv;
        pc += __shfl_xor(pc, 1, 16);
        pc += __shfl_xor(pc, 2, 16);
        pc += __shfl_xor(pc, 4, 16);
        pc += __shfl_xor(pc, 8, 16);
        if (s == 0) {
            float y = pc + xcv * Dd;
            ygp[(size_t)(b * kN + t) * kDI + d] = (__bf16)(y * zv * sigmoidf_(zv));
        }
    }
}

// ---------------- host launcher ----------------
extern "C" void kernel_launch(void* const* d_in, const int* in_sizes, int n_in,
                              void* d_out, int out_size, void* d_ws, size_t ws_size,
                              hipStream_t stream)
{
    (void)in_sizes; (void)n_in; (void)out_size; (void)ws_size;
    const float* I1  = (const float*)d_in[0];
    const float* I2  = (const float*)d_in[1];
    const float* n1w = (const float*)d_in[2];
    const float* n1b = (const float*)d_in[3];
    const float* n2w = (const float*)d_in[4];
    const float* n2b = (const float*)d_in[5];
    const float* sew1 = (const float*)d_in[6];
    const float* sew2 = (const float*)d_in[7];
    const float* in_w[2]   = {(const float*)d_in[8],  (const float*)d_in[17]};
    const float* conv_w[2] = {(const float*)d_in[9],  (const float*)d_in[18]};
    const float* conv_b[2] = {(const float*)d_in[10], (const float*)d_in[19]};
    const float* xp_w[2]   = {(const float*)d_in[11], (const float*)d_in[20]};
    const float* dt_w[2]   = {(const float*)d_in[12], (const float*)d_in[21]};
    const float* dt_b[2]   = {(const float*)d_in[13], (const float*)d_in[22]};
    const float* A_log[2]  = {(const float*)d_in[14], (const float*)d_in[23]};
    const float* Dp[2]     = {(const float*)d_in[15], (const float*)d_in[24]};
    const float* out_w[2]  = {(const float*)d_in[16], (const float*)d_in[25]};

    char* base = (char*)d_ws;
    size_t off = 0;
    auto alloc = [&](size_t bytes) -> char* {
        char* p = base + off;
        off = (off + bytes + 255) & ~(size_t)255;
        return p;
    };
    float*   s1   = (float*)alloc((size_t)4 << 20);
    float*   s2   = (float*)alloc((size_t)4 << 20);
    float*   sums = (float*)alloc(2 * 1024 * 4);      // sum1 | sum2
    float*   sum1 = sums, *sum2 = sums + 1024;
    float*   scl1 = (float*)alloc(1024 * 4);
    float*   scl2 = (float*)alloc(1024 * 4);
    __bf16*  sA[2]    = {(__bf16*)alloc((size_t)2 << 20), (__bf16*)alloc((size_t)2 << 20)};
    __bf16*  w_in[2]  = {(__bf16*)alloc((size_t)2 << 20), (__bf16*)alloc((size_t)2 << 20)};
    __bf16*  w_xp[2]  = {(__bf16*)alloc((size_t)128 << 10), (__bf16*)alloc((size_t)128 << 10)};
    __bf16*  w_out[2] = {(__bf16*)alloc((size_t)1 << 20), (__bf16*)alloc((size_t)1 << 20)};
    float*   xz[2]  = {(float*)alloc((size_t)16 << 20), (float*)alloc((size_t)16 << 20)};
    float*   xcf[2] = {(float*)alloc((size_t)8 << 20),  (float*)alloc((size_t)8 << 20)};
    __bf16*  xcb[2] = {(__bf16*)alloc((size_t)4 << 20), (__bf16*)alloc((size_t)4 << 20)};
    float*   xd[2]  = {(float*)alloc((size_t)512 << 10), (float*)alloc((size_t)512 << 10)};
    float*   dts[2] = {(float*)alloc((size_t)8 << 20),  (float*)alloc((size_t)8 << 20)};
    __bf16*  yg[2]  = {(__bf16*)alloc((size_t)4 << 20), (__bf16*)alloc((size_t)4 << 20)};
    float* o1 = (float*)d_out;
    float* o2 = o1 + (size_t)kB * kN * kDM;

    hipMemsetAsync(sums, 0, 2 * 1024 * 4, stream);
    ln_exchange_k<<<512, 256, 0, stream>>>(I1, I2, n1w, n1b, n2w, n2b, s1, s2);
    col_sum_k<<<64, 256, 0, stream>>>(s1, s2, sum1, sum2);
    se_mlp_k<<<4, 128, 0, stream>>>(sum1, sum2, sew1, sew2, scl1, scl2);
    scale_cvt_k<<<1024, 256, 0, stream>>>(s1, scl1, sA[0]);
    scale_cvt_k<<<1024, 256, 0, stream>>>(s2, scl2, sA[1]);
    for (int m = 0; m < 2; ++m) {
        cvt_bf16_k<<<1024, 256, 0, stream>>>(in_w[m],  w_in[m],  262144);
        cvt_bf16_k<<<64,   256, 0, stream>>>(xp_w[m],  w_xp[m],  16384);
        cvt_bf16_k<<<512,  256, 0, stream>>>(out_w[m], w_out[m], 131072);
    }
    for (int m = 0; m < 2; ++m)
        gemm_bt<4, 4, false><<<256, 256, 0, stream>>>(sA[m], w_in[m], nullptr, xz[m],
                                                      kB * kN, 2 * kDI, kDM);
    for (int m = 0; m < 2; ++m)
        conv_silu_k<<<8192, 256, 0, stream>>>(xz[m], conv_w[m], conv_b[m], xcf[m], xcb[m]);
    for (int m = 0; m < 2; ++m)
        gemm_bt<1, 1, false><<<128, 256, 0, stream>>>(xcb[m], w_xp[m], nullptr, xd[m],
                                                      kB * kN, 64, kDI);
    for (int m = 0; m < 2; ++m)
        dt_softplus_k<<<dim3(32, 4), 256, 0, stream>>>(xd[m], dt_w[m], dt_b[m], dts[m]);
    scan_k<<<256, 256, 0, stream>>>(dts[0], dts[1], xcf[0], xcf[1], xz[0], xz[1],
                                    xd[0], xd[1], A_log[0], A_log[1], Dp[0], Dp[1],
                                    yg[0], yg[1]);
    gemm_bt<2, 2, true><<<256, 256, 0, stream>>>(yg[0], w_out[0], I1, o1, kB * kN, kDM, kDI);
    gemm_bt<2, 2, true><<<256, 256, 0, stream>>>(yg[1], w_out[1], I2, o2, kB * kN, kDM, kDI);
}

// Round 2
// 396.751 us; speedup vs baseline: 2.5386x; 2.5386x over previous
//
#include <hip/hip_runtime.h>
#include <hip/hip_bf16.h>

// ---------------- constants ----------------
constexpr int kB   = 2;
constexpr int kN   = 1024;   // sequence length
constexpr int kDM  = 512;    // d_model
constexpr int kDI  = 1024;   // d_inner
constexpr int kDS  = 16;     // d_state
constexpr int kDTR = 32;     // dt_rank
constexpr int kNC  = 16;     // scan chunks
constexpr int kCL  = 64;     // chunk length (kN / kNC)

typedef __attribute__((ext_vector_type(8))) __bf16 bf16x8;
typedef __attribute__((ext_vector_type(4))) __bf16 bf16x4;
typedef __attribute__((ext_vector_type(4))) float  f32x4;

__device__ __forceinline__ float sigmoidf_(float x) { return 1.f / (1.f + __expf(-x)); }
__device__ __forceinline__ float sum4(float4 a) { return a.x + a.y + a.z + a.w; }
__device__ __forceinline__ float dot4(float4 a) { return a.x*a.x + a.y*a.y + a.z*a.z + a.w*a.w; }
__device__ __forceinline__ float4 nrm4(float4 x, float mu, float rs, float4 w, float4 b) {
    return make_float4((x.x-mu)*rs*w.x + b.x, (x.y-mu)*rs*w.y + b.y,
                       (x.z-mu)*rs*w.z + b.z, (x.w-mu)*rs*w.w + b.w);
}

// ---------------- layernorm + channel exchange ----------------
__launch_bounds__(256)
__global__ void ln_exchange_k(const float* __restrict__ I1, const float* __restrict__ I2,
                              const float* __restrict__ w1, const float* __restrict__ b1,
                              const float* __restrict__ w2, const float* __restrict__ b2,
                              float* __restrict__ s1, float* __restrict__ s2)
{
    int row  = blockIdx.x * 4 + (threadIdx.x >> 6);   // 0..2047
    int lane = threadIdx.x & 63;
    const float4* p1 = reinterpret_cast<const float4*>(I1 + (size_t)row * kDM);
    const float4* p2 = reinterpret_cast<const float4*>(I2 + (size_t)row * kDM);
    float4 xa1 = p1[lane], xb1 = p1[lane + 64];
    float4 xa2 = p2[lane], xb2 = p2[lane + 64];
    float su1 = sum4(xa1) + sum4(xb1), sq1 = dot4(xa1) + dot4(xb1);
    float su2 = sum4(xa2) + sum4(xb2), sq2 = dot4(xa2) + dot4(xb2);
    #pragma unroll
    for (int m = 32; m; m >>= 1) {
        su1 += __shfl_xor(su1, m, 64); sq1 += __shfl_xor(sq1, m, 64);
        su2 += __shfl_xor(su2, m, 64); sq2 += __shfl_xor(sq2, m, 64);
    }
    float mu1 = su1 * (1.f / kDM), v1 = sq1 * (1.f / kDM) - mu1 * mu1;
    float mu2 = su2 * (1.f / kDM), v2 = sq2 * (1.f / kDM) - mu2 * mu2;
    float rs1 = rsqrtf(v1 + 1e-5f), rs2 = rsqrtf(v2 + 1e-5f);
    const float4* W1 = reinterpret_cast<const float4*>(w1);
    const float4* B1 = reinterpret_cast<const float4*>(b1);
    const float4* W2 = reinterpret_cast<const float4*>(w2);
    const float4* B2 = reinterpret_cast<const float4*>(b2);
    float4 w1a = W1[lane], w1b = W1[lane+64], b1a = B1[lane], b1b = B1[lane+64];
    float4 w2a = W2[lane], w2b = W2[lane+64], b2a = B2[lane], b2b = B2[lane+64];
    float4 n1a = nrm4(xa1, mu1, rs1, w1a, b1a), n1b = nrm4(xb1, mu1, rs1, w1b, b1b);
    float4 n2a = nrm4(xa2, mu2, rs2, w2a, b2a), n2b = nrm4(xb2, mu2, rs2, w2b, b2b);
    float4 o1a = make_float4(n2a.x, n1a.y, n2a.z, n1a.w);
    float4 o2a = make_float4(n1a.x, n2a.y, n1a.z, n2a.w);
    float4 o1b = make_float4(n2b.x, n1b.y, n2b.z, n1b.w);
    float4 o2b = make_float4(n1b.x, n2b.y, n1b.z, n2b.w);
    float4* q1 = reinterpret_cast<float4*>(s1 + (size_t)row * kDM);
    float4* q2 = reinterpret_cast<float4*>(s2 + (size_t)row * kDM);
    q1[lane] = o1a; q1[lane + 64] = o1b;
    q2[lane] = o2a; q2[lane + 64] = o2b;
}

// ---------------- SE column sums ----------------
__launch_bounds__(256)
__global__ void col_sum_k(const float* __restrict__ s1, const float* __restrict__ s2,
                          float* __restrict__ sum1, float* __restrict__ sum2)
{
    int x = blockIdx.x;
    int t  = x & 1;
    int b  = (x >> 1) & 1;
    int cc = (x >> 2) & 1;
    int nc = x >> 3;                  // 0..7
    int c = cc * 256 + threadIdx.x;
    const float* src = (t ? s2 : s1) + (size_t)b * kN * kDM + (size_t)nc * 128 * kDM + c;
    float acc = 0.f;
    for (int n = 0; n < 128; ++n) acc += src[(size_t)n * kDM];
    atomicAdd((t ? sum2 : sum1) + b * kDM + c, acc);
}

// ---------------- SE MLP ----------------
__launch_bounds__(128)
__global__ void se_mlp_k(const float* __restrict__ sum1, const float* __restrict__ sum2,
                         const float* __restrict__ w1, const float* __restrict__ w2,
                         float* __restrict__ scl1, float* __restrict__ scl2)
{
    int t = blockIdx.x >> 1, b = blockIdx.x & 1;
    const float* sums = (t ? sum2 : sum1) + b * kDM;
    float* scl = (t ? scl2 : scl1) + b * kDM;
    __shared__ float m[kDM];
    __shared__ float hid[128];
    for (int c = threadIdx.x; c < kDM; c += 128) m[c] = sums[c] * (1.f / kN);
    __syncthreads();
    int j = threadIdx.x;
    float acc = 0.f;
    for (int c = 0; c < kDM; ++c) acc = fmaf(m[c], w1[j * kDM + c], acc);
    hid[j] = fmaxf(acc, 0.f);
    __syncthreads();
    for (int c = j; c < kDM; c += 128) {
        float a2 = 0.f;
        for (int k = 0; k < 128; ++k) a2 = fmaf(hid[k], w2[c * 128 + k], a2);
        scl[c] = sigmoidf_(a2);
    }
}

// ---------------- scale by SE gate + convert to bf16 ----------------
__launch_bounds__(256)
__global__ void scale_cvt_k(const float* __restrict__ s, const float* __restrict__ scl,
                            __bf16* __restrict__ out)
{
    int idx = blockIdx.x * 256 + threadIdx.x;     // 262144 float4 groups
    float4 v = reinterpret_cast<const float4*>(s)[idx];
    int c4 = idx & 127;
    int row = idx >> 7;
    int b = row >> 10;
    float4 sc = reinterpret_cast<const float4*>(scl + b * kDM)[c4];
    bf16x4 o = { (__bf16)(v.x * sc.x), (__bf16)(v.y * sc.y),
                 (__bf16)(v.z * sc.z), (__bf16)(v.w * sc.w) };
    reinterpret_cast<bf16x4*>(out)[idx] = o;
}

// ---------------- f32 -> bf16 weight convert ----------------
__launch_bounds__(256)
__global__ void cvt_bf16_k(const float* __restrict__ src, __bf16* __restrict__ dst, int n4)
{
    int idx = blockIdx.x * 256 + threadIdx.x;
    if (idx >= n4) return;
    float4 v = reinterpret_cast<const float4*>(src)[idx];
    bf16x4 o = { (__bf16)v.x, (__bf16)v.y, (__bf16)v.z, (__bf16)v.w };
    reinterpret_cast<bf16x4*>(dst)[idx] = o;
}

// ---------------- bf16 MFMA GEMM:  C[M,N] = A[M,K] @ Bw[N,K]^T (+R) ----------------
template<int WM16, int WN16, bool ADD_RES>
__global__ __launch_bounds__(256) void gemm_bt(
    const __bf16* __restrict__ A, const __bf16* __restrict__ Bw,
    const float* __restrict__ R, float* __restrict__ C,
    int M, int N, int K)
{
    constexpr int WM = 16 * WM16, WN = 16 * WN16;
    int wave = blockIdx.x * (blockDim.x >> 6) + (threadIdx.x >> 6);
    int tiles_n = N / WN;
    int tiles_m = M / WM;
    if (wave >= tiles_m * tiles_n) return;
    int tm = wave / tiles_n, tn = wave % tiles_n;
    int lane = threadIdx.x & 63;
    int r = lane & 15;
    int ko = (lane >> 4) * 8;
    const __bf16* Abase = A  + (size_t)(tm * WM + r) * K + ko;
    const __bf16* Bbase = Bw + (size_t)(tn * WN + r) * K + ko;
    f32x4 acc[WM16][WN16];
    #pragma unroll
    for (int i = 0; i < WM16; ++i)
        #pragma unroll
        for (int j = 0; j < WN16; ++j)
            acc[i][j] = (f32x4){0.f, 0.f, 0.f, 0.f};
    for (int k0 = 0; k0 < K; k0 += 32) {
        bf16x8 a[WM16], b[WN16];
        #pragma unroll
        for (int i = 0; i < WM16; ++i)
            a[i] = *reinterpret_cast<const bf16x8*>(Abase + (size_t)i * 16 * K + k0);
        #pragma unroll
        for (int j = 0; j < WN16; ++j)
            b[j] = *reinterpret_cast<const bf16x8*>(Bbase + (size_t)j * 16 * K + k0);
        #pragma unroll
        for (int i = 0; i < WM16; ++i)
            #pragma unroll
            for (int j = 0; j < WN16; ++j)
                acc[i][j] = __builtin_amdgcn_mfma_f32_16x16x32_bf16(a[i], b[j], acc[i][j], 0, 0, 0);
    }
    int row0 = tm * WM + ((lane >> 4) << 2);
    int col0 = tn * WN + (lane & 15);
    #pragma unroll
    for (int i = 0; i < WM16; ++i)
        #pragma unroll
        for (int j = 0; j < WN16; ++j)
            #pragma unroll
            for (int rr = 0; rr < 4; ++rr) {
                size_t idx = (size_t)(row0 + i * 16 + rr) * N + col0 + j * 16;
                float v = acc[i][j][rr];
                if (ADD_RES) v += R[idx];
                C[idx] = v;
            }
}

// ---------------- causal depthwise conv (width 4) + bias + SiLU ----------------
__launch_bounds__(256)
__global__ void conv_silu_k(const float* __restrict__ xz, const float* __restrict__ cw,
                            const float* __restrict__ cb,
                            float* __restrict__ xcf, __bf16* __restrict__ xcb)
{
    int idx = blockIdx.x * 256 + threadIdx.x;    // B*N*DI = 2M
    int d = idx & (kDI - 1);
    int n = (idx >> 10) & (kN - 1);
    int b = idx >> 20;
    const float* base = xz + (size_t)(b << 10) * (2 * kDI) + d;
    float acc = cb[d];
    #pragma unroll
    for (int j = 0; j < 4; ++j) {
        int nn = n - 3 + j;
        if (nn >= 0) acc = fmaf(base[(size_t)nn * (2 * kDI)], cw[d * 4 + j], acc);
    }
    float o = acc * sigmoidf_(acc);
    xcf[idx] = o;
    xcb[idx] = (__bf16)o;
}

// ---------------- dt = softplus(x_dbl[:, :32] @ dt_w^T + dt_b) ----------------
__launch_bounds__(256)
__global__ void dt_softplus_k(const float* __restrict__ xd, const float* __restrict__ dtw,
                              const float* __restrict__ dtb, float* __restrict__ dtout)
{
    int d = blockIdx.y * 256 + threadIdx.x;
    int m0 = blockIdx.x * 64;
    float w[kDTR];
    #pragma unroll
    for (int rr = 0; rr < kDTR; ++rr) w[rr] = dtw[d * kDTR + rr];
    float bias = dtb[d];
    for (int m = m0; m < m0 + 64; ++m) {
        const float* x = xd + (size_t)m * 64;
        float acc = bias;
        #pragma unroll
        for (int rr = 0; rr < kDTR; ++rr) acc = fmaf(x[rr], w[rr], acc);
        float sp = acc > 15.f ? acc : log1pf(__expf(acc));
        dtout[(size_t)m * kDI + d] = sp;
    }
}

// ---------------- chunked selective scan ----------------
// thread key g = mam<<15 | b<<14 | c<<10 | d  (group of 16 lanes, lane = state s)
// phase 1: per-chunk local scan from h=0 -> P (prod dA), H (local end state)
__launch_bounds__(256)
__global__ void scan_p1(const float* __restrict__ dt_0, const float* __restrict__ dt_1,
                        const float* __restrict__ xc_0, const float* __restrict__ xc_1,
                        const float* __restrict__ xd_0, const float* __restrict__ xd_1,
                        const float* __restrict__ Al_0, const float* __restrict__ Al_1,
                        float* __restrict__ Pbuf, float* __restrict__ Hbuf)
{
    int g = blockIdx.x * 16 + (threadIdx.x >> 4);
    int s = threadIdx.x & 15;
    int d = g & (kDI - 1);
    int c = (g >> 10) & (kNC - 1);
    int b = (g >> 14) & 1;
    int mam = g >> 15;
    const float* dtp = mam ? dt_1 : dt_0;
    const float* xcp = mam ? xc_1 : xc_0;
    const float* xdp = mam ? xd_1 : xd_0;
    const float* Alp = mam ? Al_1 : Al_0;
    float a_s = -__expf(Alp[d * kDS + s]);
    int t0 = c * kCL;
    const float* dtr = dtp + ((size_t)b * kN + t0) * kDI + d;
    const float* xcr = xcp + ((size_t)b * kN + t0) * kDI + d;
    const float* xdr = xdp + ((size_t)b * kN + t0) * 64;
    float h = 0.f, P = 1.f;
    for (int t = 0; t < kCL; ++t) {
        float dtv = dtr[(size_t)t * kDI];
        float xcv = xcr[(size_t)t * kDI];
        float Bv  = xdr[t * 64 + 32 + s];
        float dA  = __expf(dtv * a_s);
        P *= dA;
        h = fmaf(dA, h, dtv * Bv * xcv);
    }
    size_t o = (size_t)g * kDS + s;
    Pbuf[o] = P;
    Hbuf[o] = h;
}

// phase 2: cross-chunk recurrence -> per-chunk initial states
__launch_bounds__(256)
__global__ void scan_p2(const float* __restrict__ Pbuf, const float* __restrict__ Hbuf,
                        float* __restrict__ Init)
{
    int i = blockIdx.x * 256 + threadIdx.x;   // 65536 = (mam,b) x d x s
    int s = i & 15;
    int d = (i >> 4) & (kDI - 1);
    int bm = i >> 14;                          // mam*2 + b
    float h = 0.f;
    for (int c = 0; c < kNC; ++c) {
        size_t o = ((((size_t)bm * kNC + c) * kDI + d) * kDS) + s;
        Init[o] = h;
        h = fmaf(Pbuf[o], h, Hbuf[o]);
    }
}

// phase 3: re-scan each chunk with correct init, produce gated y (bf16)
__launch_bounds__(256)
__global__ void scan_p3(const float* __restrict__ dt_0, const float* __restrict__ dt_1,
                        const float* __restrict__ xc_0, const float* __restrict__ xc_1,
                        const float* __restrict__ xz_0, const float* __restrict__ xz_1,
                        const float* __restrict__ xd_0, const float* __restrict__ xd_1,
                        const float* __restrict__ Al_0, const float* __restrict__ Al_1,
                        const float* __restrict__ Dp_0, const float* __restrict__ Dp_1,
                        const float* __restrict__ Init,
                        __bf16* __restrict__ yg_0, __bf16* __restrict__ yg_1)
{
    int g = blockIdx.x * 16 + (threadIdx.x >> 4);
    int s = threadIdx.x & 15;
    int d = g & (kDI - 1);
    int c = (g >> 10) & (kNC - 1);
    int b = (g >> 14) & 1;
    int mam = g >> 15;
    const float* dtp = mam ? dt_1 : dt_0;
    const float* xcp = mam ? xc_1 : xc_0;
    const float* xzp = mam ? xz_1 : xz_0;
    const float* xdp = mam ? xd_1 : xd_0;
    const float* Alp = mam ? Al_1 : Al_0;
    const float* Dpp = mam ? Dp_1 : Dp_0;
    __bf16* ygp = mam ? yg_1 : yg_0;
    float a_s = -__expf(Alp[d * kDS + s]);
    float Dd = Dpp[d];
    int t0 = c * kCL;
    const float* dtr = dtp + ((size_t)b * kN + t0) * kDI + d;
    const float* xcr = xcp + ((size_t)b * kN + t0) * kDI + d;
    const float* zr  = xzp + ((size_t)b * kN + t0) * 2 * kDI + kDI + d;
    const float* xdr = xdp + ((size_t)b * kN + t0) * 64;
    float h = Init[(size_t)g * kDS + s];
    for (int t = 0; t < kCL; ++t) {
        float dtv = dtr[(size_t)t * kDI];
        float xcv = xcr[(size_t)t * kDI];
        float zv  = zr[(size_t)t * 2 * kDI];
        float Bv  = xdr[t * 64 + 32 + s];
        float Cv  = xdr[t * 64 + 48 + s];
        float dA  = __expf(dtv * a_s);
        h = fmaf(dA, h, dtv * Bv * xcv);
        float pc = h * Cv;
        pc += __shfl_xor(pc, 1, 16);
        pc += __shfl_xor(pc, 2, 16);
        pc += __shfl_xor(pc, 4, 16);
        pc += __shfl_xor(pc, 8, 16);
        if (s == 0) {
            float y = pc + xcv * Dd;
            ygp[((size_t)(b * kN + t0 + t)) * kDI + d] = (__bf16)(y * zv * sigmoidf_(zv));
        }
    }
}

// ---------------- host launcher ----------------
extern "C" void kernel_launch(void* const* d_in, const int* in_sizes, int n_in,
                              void* d_out, int out_size, void* d_ws, size_t ws_size,
                              hipStream_t stream)
{
    (void)in_sizes; (void)n_in; (void)out_size; (void)ws_size;
    const float* I1  = (const float*)d_in[0];
    const float* I2  = (const float*)d_in[1];
    const float* n1w = (const float*)d_in[2];
    const float* n1b = (const float*)d_in[3];
    const float* n2w = (const float*)d_in[4];
    const float* n2b = (const float*)d_in[5];
    const float* sew1 = (const float*)d_in[6];
    const float* sew2 = (const float*)d_in[7];
    const float* in_w[2]   = {(const float*)d_in[8],  (const float*)d_in[17]};
    const float* conv_w[2] = {(const float*)d_in[9],  (const float*)d_in[18]};
    const float* conv_b[2] = {(const float*)d_in[10], (const float*)d_in[19]};
    const float* xp_w[2]   = {(const float*)d_in[11], (const float*)d_in[20]};
    const float* dt_w[2]   = {(const float*)d_in[12], (const float*)d_in[21]};
    const float* dt_b[2]   = {(const float*)d_in[13], (const float*)d_in[22]};
    const float* A_log[2]  = {(const float*)d_in[14], (const float*)d_in[23]};
    const float* Dp[2]     = {(const float*)d_in[15], (const float*)d_in[24]};
    const float* out_w[2]  = {(const float*)d_in[16], (const float*)d_in[25]};

    char* base = (char*)d_ws;
    size_t off = 0;
    auto alloc = [&](size_t bytes) -> char* {
        char* p = base + off;
        off = (off + bytes + 255) & ~(size_t)255;
        return p;
    };
    float*   s1   = (float*)alloc((size_t)4 << 20);
    float*   s2   = (float*)alloc((size_t)4 << 20);
    float*   sums = (float*)alloc(2 * 1024 * 4);
    float*   sum1 = sums, *sum2 = sums + 1024;
    float*   scl1 = (float*)alloc(1024 * 4);
    float*   scl2 = (float*)alloc(1024 * 4);
    __bf16*  sA[2]    = {(__bf16*)alloc((size_t)2 << 20), (__bf16*)alloc((size_t)2 << 20)};
    __bf16*  w_in[2]  = {(__bf16*)alloc((size_t)2 << 20), (__bf16*)alloc((size_t)2 << 20)};
    __bf16*  w_xp[2]  = {(__bf16*)alloc((size_t)128 << 10), (__bf16*)alloc((size_t)128 << 10)};
    __bf16*  w_out[2] = {(__bf16*)alloc((size_t)1 << 20), (__bf16*)alloc((size_t)1 << 20)};
    float*   xz[2]  = {(float*)alloc((size_t)16 << 20), (float*)alloc((size_t)16 << 20)};
    float*   xcf[2] = {(float*)alloc((size_t)8 << 20),  (float*)alloc((size_t)8 << 20)};
    __bf16*  xcb[2] = {(__bf16*)alloc((size_t)4 << 20), (__bf16*)alloc((size_t)4 << 20)};
    float*   xd[2]  = {(float*)alloc((size_t)512 << 10), (float*)alloc((size_t)512 << 10)};
    float*   dts[2] = {(float*)alloc((size_t)8 << 20),  (float*)alloc((size_t)8 << 20)};
    __bf16*  yg[2]  = {(__bf16*)alloc((size_t)4 << 20), (__bf16*)alloc((size_t)4 << 20)};
    float*   Init   = (float*)alloc((size_t)4 << 20);   // 1M floats
    // P/H buffers reuse s1/s2 (free after scale_cvt): each needs 4 MB exactly
    float*   Pbuf = s1;
    float*   Hbuf = s2;
    float* o1 = (float*)d_out;
    float* o2 = o1 + (size_t)kB * kN * kDM;

    hipMemsetAsync(sums, 0, 2 * 1024 * 4, stream);
    ln_exchange_k<<<512, 256, 0, stream>>>(I1, I2, n1w, n1b, n2w, n2b, s1, s2);
    col_sum_k<<<64, 256, 0, stream>>>(s1, s2, sum1, sum2);
    se_mlp_k<<<4, 128, 0, stream>>>(sum1, sum2, sew1, sew2, scl1, scl2);
    scale_cvt_k<<<1024, 256, 0, stream>>>(s1, scl1, sA[0]);
    scale_cvt_k<<<1024, 256, 0, stream>>>(s2, scl2, sA[1]);
    for (int m = 0; m < 2; ++m) {
        cvt_bf16_k<<<1024, 256, 0, stream>>>(in_w[m],  w_in[m],  262144);
        cvt_bf16_k<<<64,   256, 0, stream>>>(xp_w[m],  w_xp[m],  16384);
        cvt_bf16_k<<<512,  256, 0, stream>>>(out_w[m], w_out[m], 131072);
    }
    for (int m = 0; m < 2; ++m)
        gemm_bt<4, 4, false><<<256, 256, 0, stream>>>(sA[m], w_in[m], nullptr, xz[m],
                                                      kB * kN, 2 * kDI, kDM);
    for (int m = 0; m < 2; ++m)
        conv_silu_k<<<8192, 256, 0, stream>>>(xz[m], conv_w[m], conv_b[m], xcf[m], xcb[m]);
    for (int m = 0; m < 2; ++m)
        gemm_bt<1, 1, false><<<128, 256, 0, stream>>>(xcb[m], w_xp[m], nullptr, xd[m],
                                                      kB * kN, 64, kDI);
    for (int m = 0; m < 2; ++m)
        dt_softplus_k<<<dim3(32, 4), 256, 0, stream>>>(xd[m], dt_w[m], dt_b[m], dts[m]);
    scan_p1<<<4096, 256, 0, stream>>>(dts[0], dts[1], xcf[0], xcf[1], xd[0], xd[1],
                                      A_log[0], A_log[1], Pbuf, Hbuf);
    scan_p2<<<256, 256, 0, stream>>>(Pbuf, Hbuf, Init);
    scan_p3<<<4096, 256, 0, stream>>>(dts[0], dts[1], xcf[0], xcf[1], xz[0], xz[1],
                                      xd[0], xd[1], A_log[0], A_log[1], Dp[0], Dp[1],
                                      Init, yg[0], yg[1]);
    gemm_bt<2, 2, true><<<256, 256, 0, stream>>>(yg[0], w_out[0], I1, o1, kB * kN, kDM, kDI);
    gemm_bt<2, 2, true><<<256, 256, 0, stream>>>(yg[1], w_out[1], I2, o2, kB * kN, kDM, kDI);
}

// Round 3
// 300.855 us; speedup vs baseline: 3.3478x; 1.3187x over previous
//
#include <hip/hip_runtime.h>
#include <hip/hip_bf16.h>

// ---------------- constants ----------------
constexpr int kB   = 2;
constexpr int kN   = 1024;   // sequence length
constexpr int kDM  = 512;    // d_model
constexpr int kDI  = 1024;   // d_inner
constexpr int kDS  = 16;     // d_state
constexpr int kDTR = 32;     // dt_rank
constexpr int kNC  = 32;     // scan chunks
constexpr int kCL  = 32;     // chunk length (kN / kNC)

typedef __attribute__((ext_vector_type(8))) __bf16 bf16x8;
typedef __attribute__((ext_vector_type(4))) __bf16 bf16x4;
typedef __attribute__((ext_vector_type(4))) float  f32x4;

__device__ __forceinline__ float sigmoidf_(float x) { return 1.f / (1.f + __expf(-x)); }
__device__ __forceinline__ float sum4(float4 a) { return a.x + a.y + a.z + a.w; }
__device__ __forceinline__ float dot4(float4 a) { return a.x*a.x + a.y*a.y + a.z*a.z + a.w*a.w; }
__device__ __forceinline__ float4 nrm4(float4 x, float mu, float rs, float4 w, float4 b) {
    return make_float4((x.x-mu)*rs*w.x + b.x, (x.y-mu)*rs*w.y + b.y,
                       (x.z-mu)*rs*w.z + b.z, (x.w-mu)*rs*w.w + b.w);
}

// ---------------- layernorm + channel exchange ----------------
__launch_bounds__(256)
__global__ void ln_exchange_k(const float* __restrict__ I1, const float* __restrict__ I2,
                              const float* __restrict__ w1, const float* __restrict__ b1,
                              const float* __restrict__ w2, const float* __restrict__ b2,
                              float* __restrict__ s1, float* __restrict__ s2)
{
    int row  = blockIdx.x * 4 + (threadIdx.x >> 6);   // 0..2047
    int lane = threadIdx.x & 63;
    const float4* p1 = reinterpret_cast<const float4*>(I1 + (size_t)row * kDM);
    const float4* p2 = reinterpret_cast<const float4*>(I2 + (size_t)row * kDM);
    float4 xa1 = p1[lane], xb1 = p1[lane + 64];
    float4 xa2 = p2[lane], xb2 = p2[lane + 64];
    float su1 = sum4(xa1) + sum4(xb1), sq1 = dot4(xa1) + dot4(xb1);
    float su2 = sum4(xa2) + sum4(xb2), sq2 = dot4(xa2) + dot4(xb2);
    #pragma unroll
    for (int m = 32; m; m >>= 1) {
        su1 += __shfl_xor(su1, m, 64); sq1 += __shfl_xor(sq1, m, 64);
        su2 += __shfl_xor(su2, m, 64); sq2 += __shfl_xor(sq2, m, 64);
    }
    float mu1 = su1 * (1.f / kDM), v1 = sq1 * (1.f / kDM) - mu1 * mu1;
    float mu2 = su2 * (1.f / kDM), v2 = sq2 * (1.f / kDM) - mu2 * mu2;
    float rs1 = rsqrtf(v1 + 1e-5f), rs2 = rsqrtf(v2 + 1e-5f);
    const float4* W1 = reinterpret_cast<const float4*>(w1);
    const float4* B1 = reinterpret_cast<const float4*>(b1);
    const float4* W2 = reinterpret_cast<const float4*>(w2);
    const float4* B2 = reinterpret_cast<const float4*>(b2);
    float4 w1a = W1[lane], w1b = W1[lane+64], b1a = B1[lane], b1b = B1[lane+64];
    float4 w2a = W2[lane], w2b = W2[lane+64], b2a = B2[lane], b2b = B2[lane+64];
    float4 n1a = nrm4(xa1, mu1, rs1, w1a, b1a), n1b = nrm4(xb1, mu1, rs1, w1b, b1b);
    float4 n2a = nrm4(xa2, mu2, rs2, w2a, b2a), n2b = nrm4(xb2, mu2, rs2, w2b, b2b);
    float4 o1a = make_float4(n2a.x, n1a.y, n2a.z, n1a.w);
    float4 o2a = make_float4(n1a.x, n2a.y, n1a.z, n2a.w);
    float4 o1b = make_float4(n2b.x, n1b.y, n2b.z, n1b.w);
    float4 o2b = make_float4(n1b.x, n2b.y, n1b.z, n2b.w);
    float4* q1 = reinterpret_cast<float4*>(s1 + (size_t)row * kDM);
    float4* q2 = reinterpret_cast<float4*>(s2 + (size_t)row * kDM);
    q1[lane] = o1a; q1[lane + 64] = o1b;
    q2[lane] = o2a; q2[lane + 64] = o2b;
}

// ---------------- SE column sums ----------------
__launch_bounds__(256)
__global__ void col_sum_k(const float* __restrict__ s1, const float* __restrict__ s2,
                          float* __restrict__ sum1, float* __restrict__ sum2)
{
    int x = blockIdx.x;
    int t  = x & 1;
    int b  = (x >> 1) & 1;
    int cc = (x >> 2) & 1;
    int nc = x >> 3;                  // 0..7
    int c = cc * 256 + threadIdx.x;
    const float* src = (t ? s2 : s1) + (size_t)b * kN * kDM + (size_t)nc * 128 * kDM + c;
    float acc = 0.f;
    for (int n = 0; n < 128; ++n) acc += src[(size_t)n * kDM];
    atomicAdd((t ? sum2 : sum1) + b * kDM + c, acc);
}

// ---------------- SE MLP ----------------
__launch_bounds__(128)
__global__ void se_mlp_k(const float* __restrict__ sum1, const float* __restrict__ sum2,
                         const float* __restrict__ w1, const float* __restrict__ w2,
                         float* __restrict__ scl1, float* __restrict__ scl2)
{
    int t = blockIdx.x >> 1, b = blockIdx.x & 1;
    const float* sums = (t ? sum2 : sum1) + b * kDM;
    float* scl = (t ? scl2 : scl1) + b * kDM;
    __shared__ float m[kDM];
    __shared__ float hid[128];
    for (int c = threadIdx.x; c < kDM; c += 128) m[c] = sums[c] * (1.f / kN);
    __syncthreads();
    int j = threadIdx.x;
    float acc = 0.f;
    for (int c = 0; c < kDM; ++c) acc = fmaf(m[c], w1[j * kDM + c], acc);
    hid[j] = fmaxf(acc, 0.f);
    __syncthreads();
    for (int c = j; c < kDM; c += 128) {
        float a2 = 0.f;
        for (int k = 0; k < 128; ++k) a2 = fmaf(hid[k], w2[c * 128 + k], a2);
        scl[c] = sigmoidf_(a2);
    }
}

// ---------------- scale by SE gate + convert to bf16 ----------------
__launch_bounds__(256)
__global__ void scale_cvt_k(const float* __restrict__ s, const float* __restrict__ scl,
                            __bf16* __restrict__ out)
{
    int idx = blockIdx.x * 256 + threadIdx.x;     // 262144 float4 groups
    float4 v = reinterpret_cast<const float4*>(s)[idx];
    int c4 = idx & 127;
    int row = idx >> 7;
    int b = row >> 10;
    float4 sc = reinterpret_cast<const float4*>(scl + b * kDM)[c4];
    bf16x4 o = { (__bf16)(v.x * sc.x), (__bf16)(v.y * sc.y),
                 (__bf16)(v.z * sc.z), (__bf16)(v.w * sc.w) };
    reinterpret_cast<bf16x4*>(out)[idx] = o;
}

// ---------------- fused f32 -> bf16 weight convert (all 6 weights) ----------------
__launch_bounds__(256)
__global__ void cvt_all_k(const float* __restrict__ in0, __bf16* __restrict__ win0,
                          const float* __restrict__ xp0, __bf16* __restrict__ wxp0,
                          const float* __restrict__ ow0, __bf16* __restrict__ wow0,
                          const float* __restrict__ in1, __bf16* __restrict__ win1,
                          const float* __restrict__ xp1, __bf16* __restrict__ wxp1,
                          const float* __restrict__ ow1, __bf16* __restrict__ wow1)
{
    int idx = blockIdx.x * 256 + threadIdx.x;   // float4 units, total 819200
    const float* src; __bf16* dst; int base;
    if (idx < 262144)      { src = in0; dst = win0; base = 0; }
    else if (idx < 278528) { src = xp0; dst = wxp0; base = 262144; }
    else if (idx < 409600) { src = ow0; dst = wow0; base = 278528; }
    else if (idx < 671744) { src = in1; dst = win1; base = 409600; }
    else if (idx < 688128) { src = xp1; dst = wxp1; base = 671744; }
    else                   { src = ow1; dst = wow1; base = 688128; }
    int i = idx - base;
    float4 v = reinterpret_cast<const float4*>(src)[i];
    bf16x4 o = { (__bf16)v.x, (__bf16)v.y, (__bf16)v.z, (__bf16)v.w };
    reinterpret_cast<bf16x4*>(dst)[i] = o;
}

// ---------------- bf16 MFMA GEMM:  C[M,N] = A[M,K] @ Bw[N,K]^T (+R) ----------------
template<int WM16, int WN16, bool ADD_RES>
__global__ __launch_bounds__(256) void gemm_bt(
    const __bf16* __restrict__ A, const __bf16* __restrict__ Bw,
    const float* __restrict__ R, float* __restrict__ C,
    int M, int N, int K)
{
    constexpr int WM = 16 * WM16, WN = 16 * WN16;
    int wave = blockIdx.x * (blockDim.x >> 6) + (threadIdx.x >> 6);
    int tiles_n = N / WN;
    int tiles_m = M / WM;
    if (wave >= tiles_m * tiles_n) return;
    int tm = wave / tiles_n, tn = wave % tiles_n;
    int lane = threadIdx.x & 63;
    int r = lane & 15;
    int ko = (lane >> 4) * 8;
    const __bf16* Abase = A  + (size_t)(tm * WM + r) * K + ko;
    const __bf16* Bbase = Bw + (size_t)(tn * WN + r) * K + ko;
    f32x4 acc[WM16][WN16];
    #pragma unroll
    for (int i = 0; i < WM16; ++i)
        #pragma unroll
        for (int j = 0; j < WN16; ++j)
            acc[i][j] = (f32x4){0.f, 0.f, 0.f, 0.f};
    for (int k0 = 0; k0 < K; k0 += 32) {
        bf16x8 a[WM16], b[WN16];
        #pragma unroll
        for (int i = 0; i < WM16; ++i)
            a[i] = *reinterpret_cast<const bf16x8*>(Abase + (size_t)i * 16 * K + k0);
        #pragma unroll
        for (int j = 0; j < WN16; ++j)
            b[j] = *reinterpret_cast<const bf16x8*>(Bbase + (size_t)j * 16 * K + k0);
        #pragma unroll
        for (int i = 0; i < WM16; ++i)
            #pragma unroll
            for (int j = 0; j < WN16; ++j)
                acc[i][j] = __builtin_amdgcn_mfma_f32_16x16x32_bf16(a[i], b[j], acc[i][j], 0, 0, 0);
    }
    int row0 = tm * WM + ((lane >> 4) << 2);
    int col0 = tn * WN + (lane & 15);
    #pragma unroll
    for (int i = 0; i < WM16; ++i)
        #pragma unroll
        for (int j = 0; j < WN16; ++j)
            #pragma unroll
            for (int rr = 0; rr < 4; ++rr) {
                size_t idx = (size_t)(row0 + i * 16 + rr) * N + col0 + j * 16;
                float v = acc[i][j][rr];
                if (ADD_RES) v += R[idx];
                C[idx] = v;
            }
}

// ---------------- causal depthwise conv (width 4) + bias + SiLU ----------------
__launch_bounds__(256)
__global__ void conv_silu_k(const float* __restrict__ xz, const float* __restrict__ cw,
                            const float* __restrict__ cb,
                            float* __restrict__ xcf, __bf16* __restrict__ xcb)
{
    int idx = blockIdx.x * 256 + threadIdx.x;    // B*N*DI = 2M
    int d = idx & (kDI - 1);
    int n = (idx >> 10) & (kN - 1);
    int b = idx >> 20;
    const float* base = xz + (size_t)(b << 10) * (2 * kDI) + d;
    float acc = cb[d];
    #pragma unroll
    for (int j = 0; j < 4; ++j) {
        int nn = n - 3 + j;
        if (nn >= 0) acc = fmaf(base[(size_t)nn * (2 * kDI)], cw[d * 4 + j], acc);
    }
    float o = acc * sigmoidf_(acc);
    xcf[idx] = o;
    xcb[idx] = (__bf16)o;
}

// ---------------- dt = softplus(x_dbl[:, :32] @ dt_w^T + dt_b) ----------------
__launch_bounds__(256)
__global__ void dt_softplus_k(const float* __restrict__ xd, const float* __restrict__ dtw,
                              const float* __restrict__ dtb, float* __restrict__ dtout)
{
    int d = blockIdx.y * 256 + threadIdx.x;
    int m0 = blockIdx.x * 64;
    float w[kDTR];
    #pragma unroll
    for (int rr = 0; rr < kDTR; ++rr) w[rr] = dtw[d * kDTR + rr];
    float bias = dtb[d];
    for (int m = m0; m < m0 + 64; ++m) {
        const float* x = xd + (size_t)m * 64;
        float acc = bias;
        #pragma unroll
        for (int rr = 0; rr < kDTR; ++rr) acc = fmaf(x[rr], w[rr], acc);
        float sp = acc > 15.f ? acc : log1pf(__expf(acc));
        dtout[(size_t)m * kDI + d] = sp;
    }
}

// ---------------- chunked selective scan: lane owns channel d, 16 states in regs ----
// block: 256 threads = 256 consecutive d; grid: dgrp(4) x c(kNC) x b(2) x mam(2)
// P/H/Init layout: [bm][c][s][d]  (fully coalesced everywhere)
__device__ __forceinline__ size_t ph_idx(int bm, int c, int s, int d) {
    return (((size_t)bm * kNC + c) * kDS + s) * kDI + d;
}

__launch_bounds__(256)
__global__ void scan_p1(const float* __restrict__ dt_0, const float* __restrict__ dt_1,
                        const float* __restrict__ xc_0, const float* __restrict__ xc_1,
                        const float* __restrict__ xd_0, const float* __restrict__ xd_1,
                        const float* __restrict__ Al_0, const float* __restrict__ Al_1,
                        float* __restrict__ Pbuf, float* __restrict__ Hbuf)
{
    int bid = blockIdx.x;
    int dgrp = bid & 3;
    int c    = (bid >> 2) & (kNC - 1);
    int b    = (bid >> 7) & 1;
    int mam  = bid >> 8;
    int d    = dgrp * 256 + threadIdx.x;
    int bm   = mam * 2 + b;
    const float* dtp = mam ? dt_1 : dt_0;
    const float* xcp = mam ? xc_1 : xc_0;
    const float* xdp = mam ? xd_1 : xd_0;
    const float* Alp = mam ? Al_1 : Al_0;

    float a[kDS], h[kDS], P[kDS];
    {
        const float4* Av = reinterpret_cast<const float4*>(Alp + d * kDS);
        #pragma unroll
        for (int q = 0; q < 4; ++q) {
            float4 v = Av[q];
            a[q*4+0] = -__expf(v.x); a[q*4+1] = -__expf(v.y);
            a[q*4+2] = -__expf(v.z); a[q*4+3] = -__expf(v.w);
        }
    }
    #pragma unroll
    for (int s = 0; s < kDS; ++s) { h[s] = 0.f; P[s] = 1.f; }

    int t0 = c * kCL;
    const float* dtr = dtp + ((size_t)b * kN + t0) * kDI + d;
    const float* xcr = xcp + ((size_t)b * kN + t0) * kDI + d;
    const float4* xdr = reinterpret_cast<const float4*>(xdp + ((size_t)b * kN + t0) * 64);

    #pragma unroll 4
    for (int t = 0; t < kCL; ++t) {
        float dtv = dtr[(size_t)t * kDI];
        float xcv = xcr[(size_t)t * kDI];
        float4 B0 = xdr[t * 16 + 8],  B1 = xdr[t * 16 + 9];
        float4 B2 = xdr[t * 16 + 10], B3 = xdr[t * 16 + 11];
        float Bv[kDS] = {B0.x,B0.y,B0.z,B0.w, B1.x,B1.y,B1.z,B1.w,
                         B2.x,B2.y,B2.z,B2.w, B3.x,B3.y,B3.z,B3.w};
        float dtxc = dtv * xcv;
        #pragma unroll
        for (int s = 0; s < kDS; ++s) {
            float dA = __expf(dtv * a[s]);
            P[s] *= dA;
            h[s] = fmaf(dA, h[s], dtxc * Bv[s]);
        }
    }
    #pragma unroll
    for (int s = 0; s < kDS; ++s) {
        Pbuf[ph_idx(bm, c, s, d)] = P[s];
        Hbuf[ph_idx(bm, c, s, d)] = h[s];
    }
}

// phase 2: cross-chunk recurrence -> per-chunk initial states
__launch_bounds__(256)
__global__ void scan_p2(const float* __restrict__ Pbuf, const float* __restrict__ Hbuf,
                        float* __restrict__ Init)
{
    int i = blockIdx.x * 256 + threadIdx.x;   // 65536 = bm(4) x s(16) x d(1024)
    int d = i & (kDI - 1);
    int s = (i >> 10) & 15;
    int bm = i >> 14;
    float h = 0.f;
    #pragma unroll 4
    for (int c = 0; c < kNC; ++c) {
        size_t o = ph_idx(bm, c, s, d);
        Init[o] = h;
        h = fmaf(Pbuf[o], h, Hbuf[o]);
    }
}

// phase 3: re-scan each chunk with correct init, produce gated y (bf16)
__launch_bounds__(256)
__global__ void scan_p3(const float* __restrict__ dt_0, const float* __restrict__ dt_1,
                        const float* __restrict__ xc_0, const float* __restrict__ xc_1,
                        const float* __restrict__ xz_0, const float* __restrict__ xz_1,
                        const float* __restrict__ xd_0, const float* __restrict__ xd_1,
                        const float* __restrict__ Al_0, const float* __restrict__ Al_1,
                        const float* __restrict__ Dp_0, const float* __restrict__ Dp_1,
                        const float* __restrict__ Init,
                        __bf16* __restrict__ yg_0, __bf16* __restrict__ yg_1)
{
    int bid = blockIdx.x;
    int dgrp = bid & 3;
    int c    = (bid >> 2) & (kNC - 1);
    int b    = (bid >> 7) & 1;
    int mam  = bid >> 8;
    int d    = dgrp * 256 + threadIdx.x;
    int bm   = mam * 2 + b;
    const float* dtp = mam ? dt_1 : dt_0;
    const float* xcp = mam ? xc_1 : xc_0;
    const float* xzp = mam ? xz_1 : xz_0;
    const float* xdp = mam ? xd_1 : xd_0;
    const float* Alp = mam ? Al_1 : Al_0;
    const float* Dpp = mam ? Dp_1 : Dp_0;
    __bf16* ygp = mam ? yg_1 : yg_0;

    float a[kDS], h[kDS];
    {
        const float4* Av = reinterpret_cast<const float4*>(Alp + d * kDS);
        #pragma unroll
        for (int q = 0; q < 4; ++q) {
            float4 v = Av[q];
            a[q*4+0] = -__expf(v.x); a[q*4+1] = -__expf(v.y);
            a[q*4+2] = -__expf(v.z); a[q*4+3] = -__expf(v.w);
        }
    }
    #pragma unroll
    for (int s = 0; s < kDS; ++s) h[s] = Init[ph_idx(bm, c, s, d)];
    float Dd = Dpp[d];

    int t0 = c * kCL;
    const float* dtr = dtp + ((size_t)b * kN + t0) * kDI + d;
    const float* xcr = xcp + ((size_t)b * kN + t0) * kDI + d;
    const float* zr  = xzp + ((size_t)b * kN + t0) * 2 * kDI + kDI + d;
    const float4* xdr = reinterpret_cast<const float4*>(xdp + ((size_t)b * kN + t0) * 64);
    __bf16* yr = ygp + ((size_t)b * kN + t0) * kDI + d;

    #pragma unroll 4
    for (int t = 0; t < kCL; ++t) {
        float dtv = dtr[(size_t)t * kDI];
        float xcv = xcr[(size_t)t * kDI];
        float zv  = zr[(size_t)t * 2 * kDI];
        float4 B0 = xdr[t * 16 + 8],  B1 = xdr[t * 16 + 9];
        float4 B2 = xdr[t * 16 + 10], B3 = xdr[t * 16 + 11];
        float4 C0 = xdr[t * 16 + 12], C1 = xdr[t * 16 + 13];
        float4 C2 = xdr[t * 16 + 14], C3 = xdr[t * 16 + 15];
        float Bv[kDS] = {B0.x,B0.y,B0.z,B0.w, B1.x,B1.y,B1.z,B1.w,
                         B2.x,B2.y,B2.z,B2.w, B3.x,B3.y,B3.z,B3.w};
        float Cv[kDS] = {C0.x,C0.y,C0.z,C0.w, C1.x,C1.y,C1.z,C1.w,
                         C2.x,C2.y,C2.z,C2.w, C3.x,C3.y,C3.z,C3.w};
        float dtxc = dtv * xcv;
        float acc0 = 0.f, acc1 = 0.f, acc2 = 0.f, acc3 = 0.f;
        #pragma unroll
        for (int s = 0; s < kDS; s += 4) {
            float dA0 = __expf(dtv * a[s+0]);
            float dA1 = __expf(dtv * a[s+1]);
            float dA2 = __expf(dtv * a[s+2]);
            float dA3 = __expf(dtv * a[s+3]);
            h[s+0] = fmaf(dA0, h[s+0], dtxc * Bv[s+0]);
            h[s+1] = fmaf(dA1, h[s+1], dtxc * Bv[s+1]);
            h[s+2] = fmaf(dA2, h[s+2], dtxc * Bv[s+2]);
            h[s+3] = fmaf(dA3, h[s+3], dtxc * Bv[s+3]);
            acc0 = fmaf(h[s+0], Cv[s+0], acc0);
            acc1 = fmaf(h[s+1], Cv[s+1], acc1);
            acc2 = fmaf(h[s+2], Cv[s+2], acc2);
            acc3 = fmaf(h[s+3], Cv[s+3], acc3);
        }
        float y = (acc0 + acc1) + (acc2 + acc3) + xcv * Dd;
        yr[(size_t)t * kDI] = (__bf16)(y * zv * sigmoidf_(zv));
    }
}

// ---------------- host launcher ----------------
extern "C" void kernel_launch(void* const* d_in, const int* in_sizes, int n_in,
                              void* d_out, int out_size, void* d_ws, size_t ws_size,
                              hipStream_t stream)
{
    (void)in_sizes; (void)n_in; (void)out_size; (void)ws_size;
    const float* I1  = (const float*)d_in[0];
    const float* I2  = (const float*)d_in[1];
    const float* n1w = (const float*)d_in[2];
    const float* n1b = (const float*)d_in[3];
    const float* n2w = (const float*)d_in[4];
    const float* n2b = (const float*)d_in[5];
    const float* sew1 = (const float*)d_in[6];
    const float* sew2 = (const float*)d_in[7];
    const float* in_w[2]   = {(const float*)d_in[8],  (const float*)d_in[17]};
    const float* conv_w[2] = {(const float*)d_in[9],  (const float*)d_in[18]};
    const float* conv_b[2] = {(const float*)d_in[10], (const float*)d_in[19]};
    const float* xp_w[2]   = {(const float*)d_in[11], (const float*)d_in[20]};
    const float* dt_w[2]   = {(const float*)d_in[12], (const float*)d_in[21]};
    const float* dt_b[2]   = {(const float*)d_in[13], (const float*)d_in[22]};
    const float* A_log[2]  = {(const float*)d_in[14], (const float*)d_in[23]};
    const float* Dp[2]     = {(const float*)d_in[15], (const float*)d_in[24]};
    const float* out_w[2]  = {(const float*)d_in[16], (const float*)d_in[25]};

    char* base = (char*)d_ws;
    size_t off = 0;
    auto alloc = [&](size_t bytes) -> char* {
        char* p = base + off;
        off = (off + bytes + 255) & ~(size_t)255;
        return p;
    };
    float*   s1   = (float*)alloc((size_t)4 << 20);
    float*   s2   = (float*)alloc((size_t)4 << 20);
    float*   sums = (float*)alloc(2 * 1024 * 4);
    float*   sum1 = sums, *sum2 = sums + 1024;
    float*   scl1 = (float*)alloc(1024 * 4);
    float*   scl2 = (float*)alloc(1024 * 4);
    __bf16*  sA[2]    = {(__bf16*)alloc((size_t)2 << 20), (__bf16*)alloc((size_t)2 << 20)};
    __bf16*  w_in[2]  = {(__bf16*)alloc((size_t)2 << 20), (__bf16*)alloc((size_t)2 << 20)};
    __bf16*  w_xp[2]  = {(__bf16*)alloc((size_t)128 << 10), (__bf16*)alloc((size_t)128 << 10)};
    __bf16*  w_out[2] = {(__bf16*)alloc((size_t)1 << 20), (__bf16*)alloc((size_t)1 << 20)};
    float*   xz[2]  = {(float*)alloc((size_t)16 << 20), (float*)alloc((size_t)16 << 20)};
    float*   xcf[2] = {(float*)alloc((size_t)8 << 20),  (float*)alloc((size_t)8 << 20)};
    __bf16*  xcb[2] = {(__bf16*)alloc((size_t)4 << 20), (__bf16*)alloc((size_t)4 << 20)};
    float*   xd[2]  = {(float*)alloc((size_t)512 << 10), (float*)alloc((size_t)512 << 10)};
    float*   dts[2] = {(float*)alloc((size_t)8 << 20),  (float*)alloc((size_t)8 << 20)};
    __bf16*  yg[2]  = {(__bf16*)alloc((size_t)4 << 20), (__bf16*)alloc((size_t)4 << 20)};
    float*   Hbuf   = (float*)alloc((size_t)8 << 20);
    float*   Init   = (float*)alloc((size_t)8 << 20);
    float*   Pbuf   = s1;    // reuse s1+s2 (8 MB contiguous, free after scale_cvt)
    float* o1 = (float*)d_out;
    float* o2 = o1 + (size_t)kB * kN * kDM;

    hipMemsetAsync(sums, 0, 2 * 1024 * 4, stream);
    ln_exchange_k<<<512, 256, 0, stream>>>(I1, I2, n1w, n1b, n2w, n2b, s1, s2);
    col_sum_k<<<64, 256, 0, stream>>>(s1, s2, sum1, sum2);
    se_mlp_k<<<4, 128, 0, stream>>>(sum1, sum2, sew1, sew2, scl1, scl2);
    scale_cvt_k<<<1024, 256, 0, stream>>>(s1, scl1, sA[0]);
    scale_cvt_k<<<1024, 256, 0, stream>>>(s2, scl2, sA[1]);
    cvt_all_k<<<3200, 256, 0, stream>>>(in_w[0], w_in[0], xp_w[0], w_xp[0], out_w[0], w_out[0],
                                        in_w[1], w_in[1], xp_w[1], w_xp[1], out_w[1], w_out[1]);
    for (int m = 0; m < 2; ++m)
        gemm_bt<4, 4, false><<<256, 256, 0, stream>>>(sA[m], w_in[m], nullptr, xz[m],
                                                      kB * kN, 2 * kDI, kDM);
    for (int m = 0; m < 2; ++m)
        conv_silu_k<<<8192, 256, 0, stream>>>(xz[m], conv_w[m], conv_b[m], xcf[m], xcb[m]);
    for (int m = 0; m < 2; ++m)
        gemm_bt<1, 1, false><<<128, 256, 0, stream>>>(xcb[m], w_xp[m], nullptr, xd[m],
                                                      kB * kN, 64, kDI);
    for (int m = 0; m < 2; ++m)
        dt_softplus_k<<<dim3(32, 4), 256, 0, stream>>>(xd[m], dt_w[m], dt_b[m], dts[m]);
    scan_p1<<<512, 256, 0, stream>>>(dts[0], dts[1], xcf[0], xcf[1], xd[0], xd[1],
                                     A_log[0], A_log[1], Pbuf, Hbuf);
    scan_p2<<<256, 256, 0, stream>>>(Pbuf, Hbuf, Init);
    scan_p3<<<512, 256, 0, stream>>>(dts[0], dts[1], xcf[0], xcf[1], xz[0], xz[1],
                                     xd[0], xd[1], A_log[0], A_log[1], Dp[0], Dp[1],
                                     Init, yg[0], yg[1]);
    gemm_bt<2, 2, true><<<256, 256, 0, stream>>>(yg[0], w_out[0], I1, o1, kB * kN, kDM, kDI);
    gemm_bt<2, 2, true><<<256, 256, 0, stream>>>(yg[1], w_out[1], I2, o2, kB * kN, kDM, kDI);
}

// Round 4
// 235.999 us; speedup vs baseline: 4.2678x; 1.2748x over previous
//
#include <hip/hip_runtime.h>
#include <hip/hip_bf16.h>

// ---------------- constants ----------------
constexpr int kB   = 2;
constexpr int kN   = 1024;   // sequence length
constexpr int kDM  = 512;    // d_model
constexpr int kDI  = 1024;   // d_inner
constexpr int kDS  = 16;     // d_state
constexpr int kDTR = 32;     // dt_rank
constexpr int kNC  = 32;     // scan chunks
constexpr int kCL  = 32;     // chunk length (kN / kNC)

typedef __attribute__((ext_vector_type(8))) __bf16 bf16x8;
typedef __attribute__((ext_vector_type(4))) __bf16 bf16x4;
typedef __attribute__((ext_vector_type(4))) float  f32x4;

__device__ __forceinline__ float sigmoidf_(float x) { return 1.f / (1.f + __expf(-x)); }
__device__ __forceinline__ float sum4(float4 a) { return a.x + a.y + a.z + a.w; }
__device__ __forceinline__ float dot4(float4 a) { return a.x*a.x + a.y*a.y + a.z*a.z + a.w*a.w; }
__device__ __forceinline__ float4 nrm4(float4 x, float mu, float rs, float4 w, float4 b) {
    return make_float4((x.x-mu)*rs*w.x + b.x, (x.y-mu)*rs*w.y + b.y,
                       (x.z-mu)*rs*w.z + b.z, (x.w-mu)*rs*w.w + b.w);
}

// ---------------- layernorm + channel exchange ----------------
__launch_bounds__(256)
__global__ void ln_exchange_k(const float* __restrict__ I1, const float* __restrict__ I2,
                              const float* __restrict__ w1, const float* __restrict__ b1,
                              const float* __restrict__ w2, const float* __restrict__ b2,
                              float* __restrict__ s1, float* __restrict__ s2)
{
    int row  = blockIdx.x * 4 + (threadIdx.x >> 6);   // 0..2047
    int lane = threadIdx.x & 63;
    const float4* p1 = reinterpret_cast<const float4*>(I1 + (size_t)row * kDM);
    const float4* p2 = reinterpret_cast<const float4*>(I2 + (size_t)row * kDM);
    float4 xa1 = p1[lane], xb1 = p1[lane + 64];
    float4 xa2 = p2[lane], xb2 = p2[lane + 64];
    float su1 = sum4(xa1) + sum4(xb1), sq1 = dot4(xa1) + dot4(xb1);
    float su2 = sum4(xa2) + sum4(xb2), sq2 = dot4(xa2) + dot4(xb2);
    #pragma unroll
    for (int m = 32; m; m >>= 1) {
        su1 += __shfl_xor(su1, m, 64); sq1 += __shfl_xor(sq1, m, 64);
        su2 += __shfl_xor(su2, m, 64); sq2 += __shfl_xor(sq2, m, 64);
    }
    float mu1 = su1 * (1.f / kDM), v1 = sq1 * (1.f / kDM) - mu1 * mu1;
    float mu2 = su2 * (1.f / kDM), v2 = sq2 * (1.f / kDM) - mu2 * mu2;
    float rs1 = rsqrtf(v1 + 1e-5f), rs2 = rsqrtf(v2 + 1e-5f);
    const float4* W1 = reinterpret_cast<const float4*>(w1);
    const float4* B1 = reinterpret_cast<const float4*>(b1);
    const float4* W2 = reinterpret_cast<const float4*>(w2);
    const float4* B2 = reinterpret_cast<const float4*>(b2);
    float4 w1a = W1[lane], w1b = W1[lane+64], b1a = B1[lane], b1b = B1[lane+64];
    float4 w2a = W2[lane], w2b = W2[lane+64], b2a = B2[lane], b2b = B2[lane+64];
    float4 n1a = nrm4(xa1, mu1, rs1, w1a, b1a), n1b = nrm4(xb1, mu1, rs1, w1b, b1b);
    float4 n2a = nrm4(xa2, mu2, rs2, w2a, b2a), n2b = nrm4(xb2, mu2, rs2, w2b, b2b);
    float4 o1a = make_float4(n2a.x, n1a.y, n2a.z, n1a.w);
    float4 o2a = make_float4(n1a.x, n2a.y, n1a.z, n2a.w);
    float4 o1b = make_float4(n2b.x, n1b.y, n2b.z, n1b.w);
    float4 o2b = make_float4(n1b.x, n2b.y, n1b.z, n2b.w);
    float4* q1 = reinterpret_cast<float4*>(s1 + (size_t)row * kDM);
    float4* q2 = reinterpret_cast<float4*>(s2 + (size_t)row * kDM);
    q1[lane] = o1a; q1[lane + 64] = o1b;
    q2[lane] = o2a; q2[lane + 64] = o2b;
}

// ---------------- SE column sums ----------------
__launch_bounds__(256)
__global__ void col_sum_k(const float* __restrict__ s1, const float* __restrict__ s2,
                          float* __restrict__ sum1, float* __restrict__ sum2)
{
    int x = blockIdx.x;
    int t  = x & 1;
    int b  = (x >> 1) & 1;
    int cc = (x >> 2) & 1;
    int nc = x >> 3;                  // 0..7
    int c = cc * 256 + threadIdx.x;
    const float* src = (t ? s2 : s1) + (size_t)b * kN * kDM + (size_t)nc * 128 * kDM + c;
    float acc = 0.f;
    for (int n = 0; n < 128; ++n) acc += src[(size_t)n * kDM];
    atomicAdd((t ? sum2 : sum1) + b * kDM + c, acc);
}

// ---------------- SE MLP ----------------
__launch_bounds__(128)
__global__ void se_mlp_k(const float* __restrict__ sum1, const float* __restrict__ sum2,
                         const float* __restrict__ w1, const float* __restrict__ w2,
                         float* __restrict__ scl1, float* __restrict__ scl2)
{
    int t = blockIdx.x >> 1, b = blockIdx.x & 1;
    const float* sums = (t ? sum2 : sum1) + b * kDM;
    float* scl = (t ? scl2 : scl1) + b * kDM;
    __shared__ float m[kDM];
    __shared__ float hid[128];
    for (int c = threadIdx.x; c < kDM; c += 128) m[c] = sums[c] * (1.f / kN);
    __syncthreads();
    int j = threadIdx.x;
    float acc = 0.f;
    for (int c = 0; c < kDM; ++c) acc = fmaf(m[c], w1[j * kDM + c], acc);
    hid[j] = fmaxf(acc, 0.f);
    __syncthreads();
    for (int c = j; c < kDM; c += 128) {
        float a2 = 0.f;
        for (int k = 0; k < 128; ++k) a2 = fmaf(hid[k], w2[c * 128 + k], a2);
        scl[c] = sigmoidf_(a2);
    }
}

// ---------------- scale by SE gate + convert to bf16 (both tensors) ----------------
__launch_bounds__(256)
__global__ void scale_cvt_k(const float* __restrict__ s1f, const float* __restrict__ s2f,
                            const float* __restrict__ scl1, const float* __restrict__ scl2,
                            __bf16* __restrict__ out1, __bf16* __restrict__ out2)
{
    int gidx = blockIdx.x * 256 + threadIdx.x;     // 524288 float4 groups
    int mam = gidx >> 18;
    int idx = gidx & 262143;
    const float* s = mam ? s2f : s1f;
    const float* scl = mam ? scl2 : scl1;
    __bf16* out = mam ? out2 : out1;
    float4 v = reinterpret_cast<const float4*>(s)[idx];
    int c4 = idx & 127;
    int row = idx >> 7;
    int b = row >> 10;
    float4 sc = reinterpret_cast<const float4*>(scl + b * kDM)[c4];
    bf16x4 o = { (__bf16)(v.x * sc.x), (__bf16)(v.y * sc.y),
                 (__bf16)(v.z * sc.z), (__bf16)(v.w * sc.w) };
    reinterpret_cast<bf16x4*>(out)[idx] = o;
}

// ---------------- fused f32 -> bf16 weight convert (all 6 weights) ----------------
__launch_bounds__(256)
__global__ void cvt_all_k(const float* __restrict__ in0, __bf16* __restrict__ win0,
                          const float* __restrict__ xp0, __bf16* __restrict__ wxp0,
                          const float* __restrict__ ow0, __bf16* __restrict__ wow0,
                          const float* __restrict__ in1, __bf16* __restrict__ win1,
                          const float* __restrict__ xp1, __bf16* __restrict__ wxp1,
                          const float* __restrict__ ow1, __bf16* __restrict__ wow1)
{
    int idx = blockIdx.x * 256 + threadIdx.x;   // float4 units, total 819200
    const float* src; __bf16* dst; int base;
    if (idx < 262144)      { src = in0; dst = win0; base = 0; }
    else if (idx < 278528) { src = xp0; dst = wxp0; base = 262144; }
    else if (idx < 409600) { src = ow0; dst = wow0; base = 278528; }
    else if (idx < 671744) { src = in1; dst = win1; base = 409600; }
    else if (idx < 688128) { src = xp1; dst = wxp1; base = 671744; }
    else                   { src = ow1; dst = wow1; base = 688128; }
    int i = idx - base;
    float4 v = reinterpret_cast<const float4*>(src)[i];
    bf16x4 o = { (__bf16)v.x, (__bf16)v.y, (__bf16)v.z, (__bf16)v.w };
    reinterpret_cast<bf16x4*>(dst)[i] = o;
}

// ---------------- batched bf16 MFMA GEMM (both mambas): C = A @ Bw^T (+R) --------
template<int WM16, int WN16, bool ADD_RES>
__global__ __launch_bounds__(256) void gemm_bt2(
    const __bf16* __restrict__ A0, const __bf16* __restrict__ A1,
    const __bf16* __restrict__ B0, const __bf16* __restrict__ B1,
    const float* __restrict__ R0, const float* __restrict__ R1,
    float* __restrict__ C0, float* __restrict__ C1,
    int M, int N, int K)
{
    constexpr int WM = 16 * WM16, WN = 16 * WN16;
    int tiles_n = N / WN;
    int tiles_m = M / WM;
    int per = tiles_m * tiles_n;
    int wave = blockIdx.x * (blockDim.x >> 6) + (threadIdx.x >> 6);
    int mam = wave >= per;
    if (mam) wave -= per;
    const __bf16* A  = mam ? A1 : A0;
    const __bf16* Bw = mam ? B1 : B0;
    const float*  R  = mam ? R1 : R0;
    float*        C  = mam ? C1 : C0;
    int tm = wave / tiles_n, tn = wave % tiles_n;
    int lane = threadIdx.x & 63;
    int r = lane & 15;
    int ko = (lane >> 4) * 8;
    const __bf16* Abase = A  + (size_t)(tm * WM + r) * K + ko;
    const __bf16* Bbase = Bw + (size_t)(tn * WN + r) * K + ko;
    f32x4 acc[WM16][WN16];
    #pragma unroll
    for (int i = 0; i < WM16; ++i)
        #pragma unroll
        for (int j = 0; j < WN16; ++j)
            acc[i][j] = (f32x4){0.f, 0.f, 0.f, 0.f};
    for (int k0 = 0; k0 < K; k0 += 32) {
        bf16x8 a[WM16], b[WN16];
        #pragma unroll
        for (int i = 0; i < WM16; ++i)
            a[i] = *reinterpret_cast<const bf16x8*>(Abase + (size_t)i * 16 * K + k0);
        #pragma unroll
        for (int j = 0; j < WN16; ++j)
            b[j] = *reinterpret_cast<const bf16x8*>(Bbase + (size_t)j * 16 * K + k0);
        #pragma unroll
        for (int i = 0; i < WM16; ++i)
            #pragma unroll
            for (int j = 0; j < WN16; ++j)
                acc[i][j] = __builtin_amdgcn_mfma_f32_16x16x32_bf16(a[i], b[j], acc[i][j], 0, 0, 0);
    }
    int row0 = tm * WM + ((lane >> 4) << 2);
    int col0 = tn * WN + (lane & 15);
    #pragma unroll
    for (int i = 0; i < WM16; ++i)
        #pragma unroll
        for (int j = 0; j < WN16; ++j)
            #pragma unroll
            for (int rr = 0; rr < 4; ++rr) {
                size_t idx = (size_t)(row0 + i * 16 + rr) * N + col0 + j * 16;
                float v = acc[i][j][rr];
                if (ADD_RES) v += R[idx];
                C[idx] = v;
            }
}

// ---------------- causal depthwise conv (width 4) + bias + SiLU (batched) --------
__launch_bounds__(256)
__global__ void conv_silu_k(const float* __restrict__ xz0, const float* __restrict__ xz1,
                            const float* __restrict__ cw0, const float* __restrict__ cw1,
                            const float* __restrict__ cb0, const float* __restrict__ cb1,
                            float* __restrict__ xcf0, float* __restrict__ xcf1,
                            __bf16* __restrict__ xcb0, __bf16* __restrict__ xcb1)
{
    int gidx = blockIdx.x * 256 + threadIdx.x;   // 2 * B*N*DI = 4M
    int mam = gidx >> 21;
    int idx = gidx & ((1 << 21) - 1);
    const float* xz = mam ? xz1 : xz0;
    const float* cw = mam ? cw1 : cw0;
    const float* cb = mam ? cb1 : cb0;
    float* xcf = mam ? xcf1 : xcf0;
    __bf16* xcb = mam ? xcb1 : xcb0;
    int d = idx & (kDI - 1);
    int n = (idx >> 10) & (kN - 1);
    int b = idx >> 20;
    const float* base = xz + (size_t)(b << 10) * (2 * kDI) + d;
    float acc = cb[d];
    #pragma unroll
    for (int j = 0; j < 4; ++j) {
        int nn = n - 3 + j;
        if (nn >= 0) acc = fmaf(base[(size_t)nn * (2 * kDI)], cw[d * 4 + j], acc);
    }
    float o = acc * sigmoidf_(acc);
    xcf[idx] = o;
    xcb[idx] = (__bf16)o;
}

// ---------------- dt = softplus(x_dbl[:, :32] @ dt_w^T + dt_b), batched ----------
// 1M threads; thread owns (mam, 4-row m-block, d)
__launch_bounds__(256)
__global__ void dt_softplus_k(const float* __restrict__ xd0, const float* __restrict__ xd1,
                              const float* __restrict__ dtw0, const float* __restrict__ dtw1,
                              const float* __restrict__ dtb0, const float* __restrict__ dtb1,
                              float* __restrict__ out0, float* __restrict__ out1)
{
    int idx = blockIdx.x * 256 + threadIdx.x;   // d(1024) x mblk(512) x mam(2)
    int d = idx & (kDI - 1);
    int rest = idx >> 10;
    int mblk = rest & 511;
    int mam = rest >> 9;
    const float* xd  = mam ? xd1 : xd0;
    const float* dtw = mam ? dtw1 : dtw0;
    float bias = (mam ? dtb1 : dtb0)[d];
    float* dtout = mam ? out1 : out0;
    float w[kDTR];
    const float4* wv = reinterpret_cast<const float4*>(dtw + (size_t)d * kDTR);
    #pragma unroll
    for (int q = 0; q < 8; ++q) {
        float4 v = wv[q];
        w[q*4+0] = v.x; w[q*4+1] = v.y; w[q*4+2] = v.z; w[q*4+3] = v.w;
    }
    #pragma unroll
    for (int mi = 0; mi < 4; ++mi) {
        int m = mblk * 4 + mi;
        const float4* xv = reinterpret_cast<const float4*>(xd + (size_t)m * 64);
        float acc = bias;
        #pragma unroll
        for (int q = 0; q < 8; ++q) {
            float4 v = xv[q];
            acc = fmaf(v.x, w[q*4+0], acc);
            acc = fmaf(v.y, w[q*4+1], acc);
            acc = fmaf(v.z, w[q*4+2], acc);
            acc = fmaf(v.w, w[q*4+3], acc);
        }
        float sp = acc > 15.f ? acc : log1pf(__expf(acc));
        dtout[(size_t)m * kDI + d] = sp;
    }
}

// ---------------- chunked selective scan: lane owns channel d, 16 states in regs ----
__device__ __forceinline__ size_t ph_idx(int bm, int c, int s, int d) {
    return (((size_t)bm * kNC + c) * kDS + s) * kDI + d;
}

__launch_bounds__(256)
__global__ void scan_p1(const float* __restrict__ dt_0, const float* __restrict__ dt_1,
                        const float* __restrict__ xc_0, const float* __restrict__ xc_1,
                        const float* __restrict__ xd_0, const float* __restrict__ xd_1,
                        const float* __restrict__ Al_0, const float* __restrict__ Al_1,
                        float* __restrict__ Pbuf, float* __restrict__ Hbuf)
{
    int bid = blockIdx.x;
    int dgrp = bid & 3;
    int c    = (bid >> 2) & (kNC - 1);
    int b    = (bid >> 7) & 1;
    int mam  = bid >> 8;
    int d    = dgrp * 256 + threadIdx.x;
    int bm   = mam * 2 + b;
    const float* dtp = mam ? dt_1 : dt_0;
    const float* xcp = mam ? xc_1 : xc_0;
    const float* xdp = mam ? xd_1 : xd_0;
    const float* Alp = mam ? Al_1 : Al_0;

    float a[kDS], h[kDS], P[kDS];
    {
        const float4* Av = reinterpret_cast<const float4*>(Alp + d * kDS);
        #pragma unroll
        for (int q = 0; q < 4; ++q) {
            float4 v = Av[q];
            a[q*4+0] = -__expf(v.x); a[q*4+1] = -__expf(v.y);
            a[q*4+2] = -__expf(v.z); a[q*4+3] = -__expf(v.w);
        }
    }
    #pragma unroll
    for (int s = 0; s < kDS; ++s) { h[s] = 0.f; P[s] = 1.f; }

    int t0 = c * kCL;
    const float* dtr = dtp + ((size_t)b * kN + t0) * kDI + d;
    const float* xcr = xcp + ((size_t)b * kN + t0) * kDI + d;
    const float4* xdr = reinterpret_cast<const float4*>(xdp + ((size_t)b * kN + t0) * 64);

    #pragma unroll 4
    for (int t = 0; t < kCL; ++t) {
        float dtv = dtr[(size_t)t * kDI];
        float xcv = xcr[(size_t)t * kDI];
        float4 B0 = xdr[t * 16 + 8],  B1 = xdr[t * 16 + 9];
        float4 B2 = xdr[t * 16 + 10], B3 = xdr[t * 16 + 11];
        float Bv[kDS] = {B0.x,B0.y,B0.z,B0.w, B1.x,B1.y,B1.z,B1.w,
                         B2.x,B2.y,B2.z,B2.w, B3.x,B3.y,B3.z,B3.w};
        float dtxc = dtv * xcv;
        #pragma unroll
        for (int s = 0; s < kDS; ++s) {
            float dA = __expf(dtv * a[s]);
            P[s] *= dA;
            h[s] = fmaf(dA, h[s], dtxc * Bv[s]);
        }
    }
    #pragma unroll
    for (int s = 0; s < kDS; ++s) {
        Pbuf[ph_idx(bm, c, s, d)] = P[s];
        Hbuf[ph_idx(bm, c, s, d)] = h[s];
    }
}

__launch_bounds__(256)
__global__ void scan_p2(const float* __restrict__ Pbuf, const float* __restrict__ Hbuf,
                        float* __restrict__ Init)
{
    int i = blockIdx.x * 256 + threadIdx.x;   // 65536 = bm(4) x s(16) x d(1024)
    int d = i & (kDI - 1);
    int s = (i >> 10) & 15;
    int bm = i >> 14;
    float h = 0.f;
    #pragma unroll 4
    for (int c = 0; c < kNC; ++c) {
        size_t o = ph_idx(bm, c, s, d);
        Init[o] = h;
        h = fmaf(Pbuf[o], h, Hbuf[o]);
    }
}

__launch_bounds__(256)
__global__ void scan_p3(const float* __restrict__ dt_0, const float* __restrict__ dt_1,
                        const float* __restrict__ xc_0, const float* __restrict__ xc_1,
                        const float* __restrict__ xz_0, const float* __restrict__ xz_1,
                        const float* __restrict__ xd_0, const float* __restrict__ xd_1,
                        const float* __restrict__ Al_0, const float* __restrict__ Al_1,
                        const float* __restrict__ Dp_0, const float* __restrict__ Dp_1,
                        const float* __restrict__ Init,
                        __bf16* __restrict__ yg_0, __bf16* __restrict__ yg_1)
{
    int bid = blockIdx.x;
    int dgrp = bid & 3;
    int c    = (bid >> 2) & (kNC - 1);
    int b    = (bid >> 7) & 1;
    int mam  = bid >> 8;
    int d    = dgrp * 256 + threadIdx.x;
    int bm   = mam * 2 + b;
    const float* dtp = mam ? dt_1 : dt_0;
    const float* xcp = mam ? xc_1 : xc_0;
    const float* xzp = mam ? xz_1 : xz_0;
    const float* xdp = mam ? xd_1 : xd_0;
    const float* Alp = mam ? Al_1 : Al_0;
    const float* Dpp = mam ? Dp_1 : Dp_0;
    __bf16* ygp = mam ? yg_1 : yg_0;

    float a[kDS], h[kDS];
    {
        const float4* Av = reinterpret_cast<const float4*>(Alp + d * kDS);
        #pragma unroll
        for (int q = 0; q < 4; ++q) {
            float4 v = Av[q];
            a[q*4+0] = -__expf(v.x); a[q*4+1] = -__expf(v.y);
            a[q*4+2] = -__expf(v.z); a[q*4+3] = -__expf(v.w);
        }
    }
    #pragma unroll
    for (int s = 0; s < kDS; ++s) h[s] = Init[ph_idx(bm, c, s, d)];
    float Dd = Dpp[d];

    int t0 = c * kCL;
    const float* dtr = dtp + ((size_t)b * kN + t0) * kDI + d;
    const float* xcr = xcp + ((size_t)b * kN + t0) * kDI + d;
    const float* zr  = xzp + ((size_t)b * kN + t0) * 2 * kDI + kDI + d;
    const float4* xdr = reinterpret_cast<const float4*>(xdp + ((size_t)b * kN + t0) * 64);
    __bf16* yr = ygp + ((size_t)b * kN + t0) * kDI + d;

    #pragma unroll 4
    for (int t = 0; t < kCL; ++t) {
        float dtv = dtr[(size_t)t * kDI];
        float xcv = xcr[(size_t)t * kDI];
        float zv  = zr[(size_t)t * 2 * kDI];
        float4 B0 = xdr[t * 16 + 8],  B1 = xdr[t * 16 + 9];
        float4 B2 = xdr[t * 16 + 10], B3 = xdr[t * 16 + 11];
        float4 C0 = xdr[t * 16 + 12], C1 = xdr[t * 16 + 13];
        float4 C2 = xdr[t * 16 + 14], C3 = xdr[t * 16 + 15];
        float Bv[kDS] = {B0.x,B0.y,B0.z,B0.w, B1.x,B1.y,B1.z,B1.w,
                         B2.x,B2.y,B2.z,B2.w, B3.x,B3.y,B3.z,B3.w};
        float Cv[kDS] = {C0.x,C0.y,C0.z,C0.w, C1.x,C1.y,C1.z,C1.w,
                         C2.x,C2.y,C2.z,C2.w, C3.x,C3.y,C3.z,C3.w};
        float dtxc = dtv * xcv;
        float acc0 = 0.f, acc1 = 0.f, acc2 = 0.f, acc3 = 0.f;
        #pragma unroll
        for (int s = 0; s < kDS; s += 4) {
            float dA0 = __expf(dtv * a[s+0]);
            float dA1 = __expf(dtv * a[s+1]);
            float dA2 = __expf(dtv * a[s+2]);
            float dA3 = __expf(dtv * a[s+3]);
            h[s+0] = fmaf(dA0, h[s+0], dtxc * Bv[s+0]);
            h[s+1] = fmaf(dA1, h[s+1], dtxc * Bv[s+1]);
            h[s+2] = fmaf(dA2, h[s+2], dtxc * Bv[s+2]);
            h[s+3] = fmaf(dA3, h[s+3], dtxc * Bv[s+3]);
            acc0 = fmaf(h[s+0], Cv[s+0], acc0);
            acc1 = fmaf(h[s+1], Cv[s+1], acc1);
            acc2 = fmaf(h[s+2], Cv[s+2], acc2);
            acc3 = fmaf(h[s+3], Cv[s+3], acc3);
        }
        float y = (acc0 + acc1) + (acc2 + acc3) + xcv * Dd;
        yr[(size_t)t * kDI] = (__bf16)(y * zv * sigmoidf_(zv));
    }
}

// ---------------- host launcher ----------------
extern "C" void kernel_launch(void* const* d_in, const int* in_sizes, int n_in,
                              void* d_out, int out_size, void* d_ws, size_t ws_size,
                              hipStream_t stream)
{
    (void)in_sizes; (void)n_in; (void)out_size; (void)ws_size;
    const float* I1  = (const float*)d_in[0];
    const float* I2  = (const float*)d_in[1];
    const float* n1w = (const float*)d_in[2];
    const float* n1b = (const float*)d_in[3];
    const float* n2w = (const float*)d_in[4];
    const float* n2b = (const float*)d_in[5];
    const float* sew1 = (const float*)d_in[6];
    const float* sew2 = (const float*)d_in[7];
    const float* in_w[2]   = {(const float*)d_in[8],  (const float*)d_in[17]};
    const float* conv_w[2] = {(const float*)d_in[9],  (const float*)d_in[18]};
    const float* conv_b[2] = {(const float*)d_in[10], (const float*)d_in[19]};
    const float* xp_w[2]   = {(const float*)d_in[11], (const float*)d_in[20]};
    const float* dt_w[2]   = {(const float*)d_in[12], (const float*)d_in[21]};
    const float* dt_b[2]   = {(const float*)d_in[13], (const float*)d_in[22]};
    const float* A_log[2]  = {(const float*)d_in[14], (const float*)d_in[23]};
    const float* Dp[2]     = {(const float*)d_in[15], (const float*)d_in[24]};
    const float* out_w[2]  = {(const float*)d_in[16], (const float*)d_in[25]};

    char* base = (char*)d_ws;
    size_t off = 0;
    auto alloc = [&](size_t bytes) -> char* {
        char* p = base + off;
        off = (off + bytes + 255) & ~(size_t)255;
        return p;
    };
    float*   s1   = (float*)alloc((size_t)4 << 20);
    float*   s2   = (float*)alloc((size_t)4 << 20);
    float*   sums = (float*)alloc(2 * 1024 * 4);
    float*   sum1 = sums, *sum2 = sums + 1024;
    float*   scl1 = (float*)alloc(1024 * 4);
    float*   scl2 = (float*)alloc(1024 * 4);
    __bf16*  sA[2]    = {(__bf16*)alloc((size_t)2 << 20), (__bf16*)alloc((size_t)2 << 20)};
    __bf16*  w_in[2]  = {(__bf16*)alloc((size_t)2 << 20), (__bf16*)alloc((size_t)2 << 20)};
    __bf16*  w_xp[2]  = {(__bf16*)alloc((size_t)128 << 10), (__bf16*)alloc((size_t)128 << 10)};
    __bf16*  w_out[2] = {(__bf16*)alloc((size_t)1 << 20), (__bf16*)alloc((size_t)1 << 20)};
    float*   xz[2]  = {(float*)alloc((size_t)16 << 20), (float*)alloc((size_t)16 << 20)};
    float*   xcf[2] = {(float*)alloc((size_t)8 << 20),  (float*)alloc((size_t)8 << 20)};
    __bf16*  xcb[2] = {(__bf16*)alloc((size_t)4 << 20), (__bf16*)alloc((size_t)4 << 20)};
    float*   xd[2]  = {(float*)alloc((size_t)512 << 10), (float*)alloc((size_t)512 << 10)};
    float*   dts[2] = {(float*)alloc((size_t)8 << 20),  (float*)alloc((size_t)8 << 20)};
    __bf16*  yg[2]  = {(__bf16*)alloc((size_t)4 << 20), (__bf16*)alloc((size_t)4 << 20)};
    float*   Hbuf   = (float*)alloc((size_t)8 << 20);
    float*   Init   = (float*)alloc((size_t)8 << 20);
    float*   Pbuf   = s1;    // reuse s1+s2 (8 MB contiguous, free after scale_cvt)
    float* o1 = (float*)d_out;
    float* o2 = o1 + (size_t)kB * kN * kDM;

    hipMemsetAsync(sums, 0, 2 * 1024 * 4, stream);
    ln_exchange_k<<<512, 256, 0, stream>>>(I1, I2, n1w, n1b, n2w, n2b, s1, s2);
    col_sum_k<<<64, 256, 0, stream>>>(s1, s2, sum1, sum2);
    se_mlp_k<<<4, 128, 0, stream>>>(sum1, sum2, sew1, sew2, scl1, scl2);
    scale_cvt_k<<<2048, 256, 0, stream>>>(s1, s2, scl1, scl2, sA[0], sA[1]);
    cvt_all_k<<<3200, 256, 0, stream>>>(in_w[0], w_in[0], xp_w[0], w_xp[0], out_w[0], w_out[0],
                                        in_w[1], w_in[1], xp_w[1], w_xp[1], out_w[1], w_out[1]);
    gemm_bt2<4, 4, false><<<512, 256, 0, stream>>>(sA[0], sA[1], w_in[0], w_in[1],
                                                   nullptr, nullptr, xz[0], xz[1],
                                                   kB * kN, 2 * kDI, kDM);
    conv_silu_k<<<16384, 256, 0, stream>>>(xz[0], xz[1], conv_w[0], conv_w[1],
                                           conv_b[0], conv_b[1], xcf[0], xcf[1],
                                           xcb[0], xcb[1]);
    gemm_bt2<1, 1, false><<<256, 256, 0, stream>>>(xcb[0], xcb[1], w_xp[0], w_xp[1],
                                                   nullptr, nullptr, xd[0], xd[1],
                                                   kB * kN, 64, kDI);
    dt_softplus_k<<<4096, 256, 0, stream>>>(xd[0], xd[1], dt_w[0], dt_w[1],
                                            dt_b[0], dt_b[1], dts[0], dts[1]);
    scan_p1<<<512, 256, 0, stream>>>(dts[0], dts[1], xcf[0], xcf[1], xd[0], xd[1],
                                     A_log[0], A_log[1], Pbuf, Hbuf);
    scan_p2<<<256, 256, 0, stream>>>(Pbuf, Hbuf, Init);
    scan_p3<<<512, 256, 0, stream>>>(dts[0], dts[1], xcf[0], xcf[1], xz[0], xz[1],
                                     xd[0], xd[1], A_log[0], A_log[1], Dp[0], Dp[1],
                                     Init, yg[0], yg[1]);
    gemm_bt2<2, 2, true><<<512, 256, 0, stream>>>(yg[0], yg[1], w_out[0], w_out[1],
                                                  I1, I2, o1, o2, kB * kN, kDM, kDI);
}

// Round 5
// 222.311 us; speedup vs baseline: 4.5306x; 1.0616x over previous
//
#include <hip/hip_runtime.h>
#include <hip/hip_bf16.h>

// ---------------- constants ----------------
constexpr int kB   = 2;
constexpr int kN   = 1024;   // sequence length
constexpr int kDM  = 512;    // d_model
constexpr int kDI  = 1024;   // d_inner
constexpr int kDS  = 16;     // d_state
constexpr int kDTR = 32;     // dt_rank
constexpr int kNC  = 32;     // scan chunks
constexpr int kCL  = 32;     // chunk length (kN / kNC)

typedef __attribute__((ext_vector_type(8))) __bf16 bf16x8;
typedef __attribute__((ext_vector_type(4))) __bf16 bf16x4;
typedef __attribute__((ext_vector_type(4))) float  f32x4;

__device__ __forceinline__ float sigmoidf_(float x) { return 1.f / (1.f + __expf(-x)); }
__device__ __forceinline__ float sum4(float4 a) { return a.x + a.y + a.z + a.w; }
__device__ __forceinline__ float dot4(float4 a) { return a.x*a.x + a.y*a.y + a.z*a.z + a.w*a.w; }
__device__ __forceinline__ float4 nrm4(float4 x, float mu, float rs, float4 w, float4 b) {
    return make_float4((x.x-mu)*rs*w.x + b.x, (x.y-mu)*rs*w.y + b.y,
                       (x.z-mu)*rs*w.z + b.z, (x.w-mu)*rs*w.w + b.w);
}

// ---------------- layernorm + channel exchange ----------------
__launch_bounds__(256)
__global__ void ln_exchange_k(const float* __restrict__ I1, const float* __restrict__ I2,
                              const float* __restrict__ w1, const float* __restrict__ b1,
                              const float* __restrict__ w2, const float* __restrict__ b2,
                              float* __restrict__ s1, float* __restrict__ s2)
{
    int row  = blockIdx.x * 4 + (threadIdx.x >> 6);   // 0..2047
    int lane = threadIdx.x & 63;
    const float4* p1 = reinterpret_cast<const float4*>(I1 + (size_t)row * kDM);
    const float4* p2 = reinterpret_cast<const float4*>(I2 + (size_t)row * kDM);
    float4 xa1 = p1[lane], xb1 = p1[lane + 64];
    float4 xa2 = p2[lane], xb2 = p2[lane + 64];
    float su1 = sum4(xa1) + sum4(xb1), sq1 = dot4(xa1) + dot4(xb1);
    float su2 = sum4(xa2) + sum4(xb2), sq2 = dot4(xa2) + dot4(xb2);
    #pragma unroll
    for (int m = 32; m; m >>= 1) {
        su1 += __shfl_xor(su1, m, 64); sq1 += __shfl_xor(sq1, m, 64);
        su2 += __shfl_xor(su2, m, 64); sq2 += __shfl_xor(sq2, m, 64);
    }
    float mu1 = su1 * (1.f / kDM), v1 = sq1 * (1.f / kDM) - mu1 * mu1;
    float mu2 = su2 * (1.f / kDM), v2 = sq2 * (1.f / kDM) - mu2 * mu2;
    float rs1 = rsqrtf(v1 + 1e-5f), rs2 = rsqrtf(v2 + 1e-5f);
    const float4* W1 = reinterpret_cast<const float4*>(w1);
    const float4* B1 = reinterpret_cast<const float4*>(b1);
    const float4* W2 = reinterpret_cast<const float4*>(w2);
    const float4* B2 = reinterpret_cast<const float4*>(b2);
    float4 w1a = W1[lane], w1b = W1[lane+64], b1a = B1[lane], b1b = B1[lane+64];
    float4 w2a = W2[lane], w2b = W2[lane+64], b2a = B2[lane], b2b = B2[lane+64];
    float4 n1a = nrm4(xa1, mu1, rs1, w1a, b1a), n1b = nrm4(xb1, mu1, rs1, w1b, b1b);
    float4 n2a = nrm4(xa2, mu2, rs2, w2a, b2a), n2b = nrm4(xb2, mu2, rs2, w2b, b2b);
    float4 o1a = make_float4(n2a.x, n1a.y, n2a.z, n1a.w);
    float4 o2a = make_float4(n1a.x, n2a.y, n1a.z, n2a.w);
    float4 o1b = make_float4(n2b.x, n1b.y, n2b.z, n1b.w);
    float4 o2b = make_float4(n1b.x, n2b.y, n1b.z, n2b.w);
    float4* q1 = reinterpret_cast<float4*>(s1 + (size_t)row * kDM);
    float4* q2 = reinterpret_cast<float4*>(s2 + (size_t)row * kDM);
    q1[lane] = o1a; q1[lane + 64] = o1b;
    q2[lane] = o2a; q2[lane + 64] = o2b;
}

// ---------------- SE column partial sums (no atomics, no memset) ----------------
// grid: 64 blocks = t(2) x b(2) x cc(2) x nc(8); partial layout [t][b][nc][512]
__launch_bounds__(256)
__global__ void col_sum_k(const float* __restrict__ s1, const float* __restrict__ s2,
                          float* __restrict__ partial)
{
    int x = blockIdx.x;
    int t  = x & 1;
    int b  = (x >> 1) & 1;
    int cc = (x >> 2) & 1;
    int nc = x >> 3;                  // 0..7
    int c = cc * 256 + threadIdx.x;
    const float* src = (t ? s2 : s1) + (size_t)b * kN * kDM + (size_t)nc * 128 * kDM + c;
    float acc = 0.f;
    for (int n = 0; n < 128; ++n) acc += src[(size_t)n * kDM];
    partial[(((size_t)(t * 2 + b)) * 8 + nc) * kDM + c] = acc;
}

// ---------------- SE MLP (reduces the 8 partials) ----------------
__launch_bounds__(128)
__global__ void se_mlp_k(const float* __restrict__ partial,
                         const float* __restrict__ w1, const float* __restrict__ w2,
                         float* __restrict__ scl1, float* __restrict__ scl2)
{
    int t = blockIdx.x >> 1, b = blockIdx.x & 1;
    const float* part = partial + ((size_t)(t * 2 + b)) * 8 * kDM;
    float* scl = (t ? scl2 : scl1) + b * kDM;
    __shared__ float m[kDM];
    __shared__ float hid[128];
    for (int c = threadIdx.x; c < kDM; c += 128) {
        float acc = 0.f;
        #pragma unroll
        for (int nc = 0; nc < 8; ++nc) acc += part[nc * kDM + c];
        m[c] = acc * (1.f / kN);
    }
    __syncthreads();
    int j = threadIdx.x;
    float acc = 0.f;
    for (int c = 0; c < kDM; ++c) acc = fmaf(m[c], w1[j * kDM + c], acc);
    hid[j] = fmaxf(acc, 0.f);
    __syncthreads();
    for (int c = j; c < kDM; c += 128) {
        float a2 = 0.f;
        for (int k = 0; k < 128; ++k) a2 = fmaf(hid[k], w2[c * 128 + k], a2);
        scl[c] = sigmoidf_(a2);
    }
}

// ---------------- scale by SE gate + convert to bf16 (both tensors) ----------------
__launch_bounds__(256)
__global__ void scale_cvt_k(const float* __restrict__ s1f, const float* __restrict__ s2f,
                            const float* __restrict__ scl1, const float* __restrict__ scl2,
                            __bf16* __restrict__ out1, __bf16* __restrict__ out2)
{
    int gidx = blockIdx.x * 256 + threadIdx.x;     // 524288 float4 groups
    int mam = gidx >> 18;
    int idx = gidx & 262143;
    const float* s = mam ? s2f : s1f;
    const float* scl = mam ? scl2 : scl1;
    __bf16* out = mam ? out2 : out1;
    float4 v = reinterpret_cast<const float4*>(s)[idx];
    int c4 = idx & 127;
    int row = idx >> 7;
    int b = row >> 10;
    float4 sc = reinterpret_cast<const float4*>(scl + b * kDM)[c4];
    bf16x4 o = { (__bf16)(v.x * sc.x), (__bf16)(v.y * sc.y),
                 (__bf16)(v.z * sc.z), (__bf16)(v.w * sc.w) };
    reinterpret_cast<bf16x4*>(out)[idx] = o;
}

// ---------------- fused f32 -> bf16 weight convert (all 6 weights) ----------------
__launch_bounds__(256)
__global__ void cvt_all_k(const float* __restrict__ in0, __bf16* __restrict__ win0,
                          const float* __restrict__ xp0, __bf16* __restrict__ wxp0,
                          const float* __restrict__ ow0, __bf16* __restrict__ wow0,
                          const float* __restrict__ in1, __bf16* __restrict__ win1,
                          const float* __restrict__ xp1, __bf16* __restrict__ wxp1,
                          const float* __restrict__ ow1, __bf16* __restrict__ wow1)
{
    int idx = blockIdx.x * 256 + threadIdx.x;   // float4 units, total 819200
    const float* src; __bf16* dst; int base;
    if (idx < 262144)      { src = in0; dst = win0; base = 0; }
    else if (idx < 278528) { src = xp0; dst = wxp0; base = 262144; }
    else if (idx < 409600) { src = ow0; dst = wow0; base = 278528; }
    else if (idx < 671744) { src = in1; dst = win1; base = 409600; }
    else if (idx < 688128) { src = xp1; dst = wxp1; base = 671744; }
    else                   { src = ow1; dst = wow1; base = 688128; }
    int i = idx - base;
    float4 v = reinterpret_cast<const float4*>(src)[i];
    bf16x4 o = { (__bf16)v.x, (__bf16)v.y, (__bf16)v.z, (__bf16)v.w };
    reinterpret_cast<bf16x4*>(dst)[i] = o;
}

// ---------------- batched bf16 MFMA GEMM (both mambas): C = A @ Bw^T (+R) --------
template<int WM16, int WN16, bool ADD_RES>
__global__ __launch_bounds__(256) void gemm_bt2(
    const __bf16* __restrict__ A0, const __bf16* __restrict__ A1,
    const __bf16* __restrict__ B0, const __bf16* __restrict__ B1,
    const float* __restrict__ R0, const float* __restrict__ R1,
    float* __restrict__ C0, float* __restrict__ C1,
    int M, int N, int K)
{
    constexpr int WM = 16 * WM16, WN = 16 * WN16;
    int tiles_n = N / WN;
    int tiles_m = M / WM;
    int per = tiles_m * tiles_n;
    int wave = blockIdx.x * (blockDim.x >> 6) + (threadIdx.x >> 6);
    int mam = wave >= per;
    if (mam) wave -= per;
    const __bf16* A  = mam ? A1 : A0;
    const __bf16* Bw = mam ? B1 : B0;
    const float*  R  = mam ? R1 : R0;
    float*        C  = mam ? C1 : C0;
    int tm = wave / tiles_n, tn = wave % tiles_n;
    int lane = threadIdx.x & 63;
    int r = lane & 15;
    int ko = (lane >> 4) * 8;
    const __bf16* Abase = A  + (size_t)(tm * WM + r) * K + ko;
    const __bf16* Bbase = Bw + (size_t)(tn * WN + r) * K + ko;
    f32x4 acc[WM16][WN16];
    #pragma unroll
    for (int i = 0; i < WM16; ++i)
        #pragma unroll
        for (int j = 0; j < WN16; ++j)
            acc[i][j] = (f32x4){0.f, 0.f, 0.f, 0.f};
    for (int k0 = 0; k0 < K; k0 += 32) {
        bf16x8 a[WM16], b[WN16];
        #pragma unroll
        for (int i = 0; i < WM16; ++i)
            a[i] = *reinterpret_cast<const bf16x8*>(Abase + (size_t)i * 16 * K + k0);
        #pragma unroll
        for (int j = 0; j < WN16; ++j)
            b[j] = *reinterpret_cast<const bf16x8*>(Bbase + (size_t)j * 16 * K + k0);
        #pragma unroll
        for (int i = 0; i < WM16; ++i)
            #pragma unroll
            for (int j = 0; j < WN16; ++j)
                acc[i][j] = __builtin_amdgcn_mfma_f32_16x16x32_bf16(a[i], b[j], acc[i][j], 0, 0, 0);
    }
    int row0 = tm * WM + ((lane >> 4) << 2);
    int col0 = tn * WN + (lane & 15);
    #pragma unroll
    for (int i = 0; i < WM16; ++i)
        #pragma unroll
        for (int j = 0; j < WN16; ++j)
            #pragma unroll
            for (int rr = 0; rr < 4; ++rr) {
                size_t idx = (size_t)(row0 + i * 16 + rr) * N + col0 + j * 16;
                float v = acc[i][j][rr];
                if (ADD_RES) v += R[idx];
                C[idx] = v;
            }
}

// ---------------- causal depthwise conv (width 4) + bias + SiLU (batched) --------
__launch_bounds__(256)
__global__ void conv_silu_k(const float* __restrict__ xz0, const float* __restrict__ xz1,
                            const float* __restrict__ cw0, const float* __restrict__ cw1,
                            const float* __restrict__ cb0, const float* __restrict__ cb1,
                            float* __restrict__ xcf0, float* __restrict__ xcf1,
                            __bf16* __restrict__ xcb0, __bf16* __restrict__ xcb1)
{
    int gidx = blockIdx.x * 256 + threadIdx.x;   // 2 * B*N*DI = 4M
    int mam = gidx >> 21;
    int idx = gidx & ((1 << 21) - 1);
    const float* xz = mam ? xz1 : xz0;
    const float* cw = mam ? cw1 : cw0;
    const float* cb = mam ? cb1 : cb0;
    float* xcf = mam ? xcf1 : xcf0;
    __bf16* xcb = mam ? xcb1 : xcb0;
    int d = idx & (kDI - 1);
    int n = (idx >> 10) & (kN - 1);
    int b = idx >> 20;
    const float* base = xz + (size_t)(b << 10) * (2 * kDI) + d;
    float acc = cb[d];
    #pragma unroll
    for (int j = 0; j < 4; ++j) {
        int nn = n - 3 + j;
        if (nn >= 0) acc = fmaf(base[(size_t)nn * (2 * kDI)], cw[d * 4 + j], acc);
    }
    float o = acc * sigmoidf_(acc);
    xcf[idx] = o;
    xcb[idx] = (__bf16)o;
}

// ---------------- dt = softplus(x_dbl[:, :32] @ dt_w^T + dt_b), batched ----------
__launch_bounds__(256)
__global__ void dt_softplus_k(const float* __restrict__ xd0, const float* __restrict__ xd1,
                              const float* __restrict__ dtw0, const float* __restrict__ dtw1,
                              const float* __restrict__ dtb0, const float* __restrict__ dtb1,
                              float* __restrict__ out0, float* __restrict__ out1)
{
    int idx = blockIdx.x * 256 + threadIdx.x;   // d(1024) x mblk(512) x mam(2)
    int d = idx & (kDI - 1);
    int rest = idx >> 10;
    int mblk = rest & 511;
    int mam = rest >> 9;
    const float* xd  = mam ? xd1 : xd0;
    const float* dtw = mam ? dtw1 : dtw0;
    float bias = (mam ? dtb1 : dtb0)[d];
    float* dtout = mam ? out1 : out0;
    float w[kDTR];
    const float4* wv = reinterpret_cast<const float4*>(dtw + (size_t)d * kDTR);
    #pragma unroll
    for (int q = 0; q < 8; ++q) {
        float4 v = wv[q];
        w[q*4+0] = v.x; w[q*4+1] = v.y; w[q*4+2] = v.z; w[q*4+3] = v.w;
    }
    #pragma unroll
    for (int mi = 0; mi < 4; ++mi) {
        int m = mblk * 4 + mi;
        const float4* xv = reinterpret_cast<const float4*>(xd + (size_t)m * 64);
        float acc = bias;
        #pragma unroll
        for (int q = 0; q < 8; ++q) {
            float4 v = xv[q];
            acc = fmaf(v.x, w[q*4+0], acc);
            acc = fmaf(v.y, w[q*4+1], acc);
            acc = fmaf(v.z, w[q*4+2], acc);
            acc = fmaf(v.w, w[q*4+3], acc);
        }
        float sp = acc > 15.f ? acc : log1pf(__expf(acc));
        dtout[(size_t)m * kDI + d] = sp;
    }
}

// ---------------- chunked selective scan: lane owns channel d, 16 states in regs ----
__device__ __forceinline__ size_t ph_idx(int bm, int c, int s, int d) {
    return (((size_t)bm * kNC + c) * kDS + s) * kDI + d;
}

__launch_bounds__(256)
__global__ void scan_p1(const float* __restrict__ dt_0, const float* __restrict__ dt_1,
                        const float* __restrict__ xc_0, const float* __restrict__ xc_1,
                        const float* __restrict__ xd_0, const float* __restrict__ xd_1,
                        const float* __restrict__ Al_0, const float* __restrict__ Al_1,
                        float* __restrict__ Pbuf, float* __restrict__ Hbuf)
{
    int bid = blockIdx.x;
    int dgrp = bid & 3;
    int c    = (bid >> 2) & (kNC - 1);
    int b    = (bid >> 7) & 1;
    int mam  = bid >> 8;
    int d    = dgrp * 256 + threadIdx.x;
    int bm   = mam * 2 + b;
    const float* dtp = mam ? dt_1 : dt_0;
    const float* xcp = mam ? xc_1 : xc_0;
    const float* xdp = mam ? xd_1 : xd_0;
    const float* Alp = mam ? Al_1 : Al_0;

    float a[kDS], h[kDS], P[kDS];
    {
        const float4* Av = reinterpret_cast<const float4*>(Alp + d * kDS);
        #pragma unroll
        for (int q = 0; q < 4; ++q) {
            float4 v = Av[q];
            a[q*4+0] = -__expf(v.x); a[q*4+1] = -__expf(v.y);
            a[q*4+2] = -__expf(v.z); a[q*4+3] = -__expf(v.w);
        }
    }
    #pragma unroll
    for (int s = 0; s < kDS; ++s) { h[s] = 0.f; P[s] = 1.f; }

    int t0 = c * kCL;
    const float* dtr = dtp + ((size_t)b * kN + t0) * kDI + d;
    const float* xcr = xcp + ((size_t)b * kN + t0) * kDI + d;
    const float4* xdr = reinterpret_cast<const float4*>(xdp + ((size_t)b * kN + t0) * 64);

    #pragma unroll 4
    for (int t = 0; t < kCL; ++t) {
        float dtv = dtr[(size_t)t * kDI];
        float xcv = xcr[(size_t)t * kDI];
        float4 B0 = xdr[t * 16 + 8],  B1 = xdr[t * 16 + 9];
        float4 B2 = xdr[t * 16 + 10], B3 = xdr[t * 16 + 11];
        float Bv[kDS] = {B0.x,B0.y,B0.z,B0.w, B1.x,B1.y,B1.z,B1.w,
                         B2.x,B2.y,B2.z,B2.w, B3.x,B3.y,B3.z,B3.w};
        float dtxc = dtv * xcv;
        #pragma unroll
        for (int s = 0; s < kDS; ++s) {
            float dA = __expf(dtv * a[s]);
            P[s] *= dA;
            h[s] = fmaf(dA, h[s], dtxc * Bv[s]);
        }
    }
    #pragma unroll
    for (int s = 0; s < kDS; ++s) {
        Pbuf[ph_idx(bm, c, s, d)] = P[s];
        Hbuf[ph_idx(bm, c, s, d)] = h[s];
    }
}

__launch_bounds__(256)
__global__ void scan_p2(const float* __restrict__ Pbuf, const float* __restrict__ Hbuf,
                        float* __restrict__ Init)
{
    int i = blockIdx.x * 256 + threadIdx.x;   // 65536 = bm(4) x s(16) x d(1024)
    int d = i & (kDI - 1);
    int s = (i >> 10) & 15;
    int bm = i >> 14;
    float h = 0.f;
    #pragma unroll 4
    for (int c = 0; c < kNC; ++c) {
        size_t o = ph_idx(bm, c, s, d);
        Init[o] = h;
        h = fmaf(Pbuf[o], h, Hbuf[o]);
    }
}

__launch_bounds__(256)
__global__ void scan_p3(const float* __restrict__ dt_0, const float* __restrict__ dt_1,
                        const float* __restrict__ xc_0, const float* __restrict__ xc_1,
                        const float* __restrict__ xz_0, const float* __restrict__ xz_1,
                        const float* __restrict__ xd_0, const float* __restrict__ xd_1,
                        const float* __restrict__ Al_0, const float* __restrict__ Al_1,
                        const float* __restrict__ Dp_0, const float* __restrict__ Dp_1,
                        const float* __restrict__ Init,
                        __bf16* __restrict__ yg_0, __bf16* __restrict__ yg_1)
{
    int bid = blockIdx.x;
    int dgrp = bid & 3;
    int c    = (bid >> 2) & (kNC - 1);
    int b    = (bid >> 7) & 1;
    int mam  = bid >> 8;
    int d    = dgrp * 256 + threadIdx.x;
    int bm   = mam * 2 + b;
    const float* dtp = mam ? dt_1 : dt_0;
    const float* xcp = mam ? xc_1 : xc_0;
    const float* xzp = mam ? xz_1 : xz_0;
    const float* xdp = mam ? xd_1 : xd_0;
    const float* Alp = mam ? Al_1 : Al_0;
    const float* Dpp = mam ? Dp_1 : Dp_0;
    __bf16* ygp = mam ? yg_1 : yg_0;

    float a[kDS], h[kDS];
    {
        const float4* Av = reinterpret_cast<const float4*>(Alp + d * kDS);
        #pragma unroll
        for (int q = 0; q < 4; ++q) {
            float4 v = Av[q];
            a[q*4+0] = -__expf(v.x); a[q*4+1] = -__expf(v.y);
            a[q*4+2] = -__expf(v.z); a[q*4+3] = -__expf(v.w);
        }
    }
    #pragma unroll
    for (int s = 0; s < kDS; ++s) h[s] = Init[ph_idx(bm, c, s, d)];
    float Dd = Dpp[d];

    int t0 = c * kCL;
    const float* dtr = dtp + ((size_t)b * kN + t0) * kDI + d;
    const float* xcr = xcp + ((size_t)b * kN + t0) * kDI + d;
    const float* zr  = xzp + ((size_t)b * kN + t0) * 2 * kDI + kDI + d;
    const float4* xdr = reinterpret_cast<const float4*>(xdp + ((size_t)b * kN + t0) * 64);
    __bf16* yr = ygp + ((size_t)b * kN + t0) * kDI + d;

    #pragma unroll 4
    for (int t = 0; t < kCL; ++t) {
        float dtv = dtr[(size_t)t * kDI];
        float xcv = xcr[(size_t)t * kDI];
        float zv  = zr[(size_t)t * 2 * kDI];
        float4 B0 = xdr[t * 16 + 8],  B1 = xdr[t * 16 + 9];
        float4 B2 = xdr[t * 16 + 10], B3 = xdr[t * 16 + 11];
        float4 C0 = xdr[t * 16 + 12], C1 = xdr[t * 16 + 13];
        float4 C2 = xdr[t * 16 + 14], C3 = xdr[t * 16 + 15];
        float Bv[kDS] = {B0.x,B0.y,B0.z,B0.w, B1.x,B1.y,B1.z,B1.w,
                         B2.x,B2.y,B2.z,B2.w, B3.x,B3.y,B3.z,B3.w};
        float Cv[kDS] = {C0.x,C0.y,C0.z,C0.w, C1.x,C1.y,C1.z,C1.w,
                         C2.x,C2.y,C2.z,C2.w, C3.x,C3.y,C3.z,C3.w};
        float dtxc = dtv * xcv;
        float acc0 = 0.f, acc1 = 0.f, acc2 = 0.f, acc3 = 0.f;
        #pragma unroll
        for (int s = 0; s < kDS; s += 4) {
            float dA0 = __expf(dtv * a[s+0]);
            float dA1 = __expf(dtv * a[s+1]);
            float dA2 = __expf(dtv * a[s+2]);
            float dA3 = __expf(dtv * a[s+3]);
            h[s+0] = fmaf(dA0, h[s+0], dtxc * Bv[s+0]);
            h[s+1] = fmaf(dA1, h[s+1], dtxc * Bv[s+1]);
            h[s+2] = fmaf(dA2, h[s+2], dtxc * Bv[s+2]);
            h[s+3] = fmaf(dA3, h[s+3], dtxc * Bv[s+3]);
            acc0 = fmaf(h[s+0], Cv[s+0], acc0);
            acc1 = fmaf(h[s+1], Cv[s+1], acc1);
            acc2 = fmaf(h[s+2], Cv[s+2], acc2);
            acc3 = fmaf(h[s+3], Cv[s+3], acc3);
        }
        float y = (acc0 + acc1) + (acc2 + acc3) + xcv * Dd;
        yr[(size_t)t * kDI] = (__bf16)(y * zv * sigmoidf_(zv));
    }
}

// ---------------- host launcher ----------------
extern "C" void kernel_launch(void* const* d_in, const int* in_sizes, int n_in,
                              void* d_out, int out_size, void* d_ws, size_t ws_size,
                              hipStream_t stream)
{
    (void)in_sizes; (void)n_in; (void)out_size; (void)ws_size;
    const float* I1  = (const float*)d_in[0];
    const float* I2  = (const float*)d_in[1];
    const float* n1w = (const float*)d_in[2];
    const float* n1b = (const float*)d_in[3];
    const float* n2w = (const float*)d_in[4];
    const float* n2b = (const float*)d_in[5];
    const float* sew1 = (const float*)d_in[6];
    const float* sew2 = (const float*)d_in[7];
    const float* in_w[2]   = {(const float*)d_in[8],  (const float*)d_in[17]};
    const float* conv_w[2] = {(const float*)d_in[9],  (const float*)d_in[18]};
    const float* conv_b[2] = {(const float*)d_in[10], (const float*)d_in[19]};
    const float* xp_w[2]   = {(const float*)d_in[11], (const float*)d_in[20]};
    const float* dt_w[2]   = {(const float*)d_in[12], (const float*)d_in[21]};
    const float* dt_b[2]   = {(const float*)d_in[13], (const float*)d_in[22]};
    const float* A_log[2]  = {(const float*)d_in[14], (const float*)d_in[23]};
    const float* Dp[2]     = {(const float*)d_in[15], (const float*)d_in[24]};
    const float* out_w[2]  = {(const float*)d_in[16], (const float*)d_in[25]};

    char* base = (char*)d_ws;
    size_t off = 0;
    auto alloc = [&](size_t bytes) -> char* {
        char* p = base + off;
        off = (off + bytes + 255) & ~(size_t)255;
        return p;
    };
    float*   s1   = (float*)alloc((size_t)4 << 20);
    float*   s2   = (float*)alloc((size_t)4 << 20);
    float*   partial = (float*)alloc(2 * 2 * 8 * kDM * 4);   // 64 KB
    float*   scl1 = (float*)alloc(1024 * 4);
    float*   scl2 = (float*)alloc(1024 * 4);
    __bf16*  sA[2]    = {(__bf16*)alloc((size_t)2 << 20), (__bf16*)alloc((size_t)2 << 20)};
    __bf16*  w_in[2]  = {(__bf16*)alloc((size_t)2 << 20), (__bf16*)alloc((size_t)2 << 20)};
    __bf16*  w_xp[2]  = {(__bf16*)alloc((size_t)128 << 10), (__bf16*)alloc((size_t)128 << 10)};
    __bf16*  w_out[2] = {(__bf16*)alloc((size_t)1 << 20), (__bf16*)alloc((size_t)1 << 20)};
    float*   xz[2]  = {(float*)alloc((size_t)16 << 20), (float*)alloc((size_t)16 << 20)};
    float*   xcf[2] = {(float*)alloc((size_t)8 << 20),  (float*)alloc((size_t)8 << 20)};
    __bf16*  xcb[2] = {(__bf16*)alloc((size_t)4 << 20), (__bf16*)alloc((size_t)4 << 20)};
    float*   xd[2]  = {(float*)alloc((size_t)512 << 10), (float*)alloc((size_t)512 << 10)};
    float*   dts[2] = {(float*)alloc((size_t)8 << 20),  (float*)alloc((size_t)8 << 20)};
    __bf16*  yg[2]  = {(__bf16*)alloc((size_t)4 << 20), (__bf16*)alloc((size_t)4 << 20)};
    float*   Hbuf   = (float*)alloc((size_t)8 << 20);
    float*   Init   = (float*)alloc((size_t)8 << 20);
    float*   Pbuf   = s1;    // reuse s1+s2 (8 MB contiguous, free after scale_cvt)
    float* o1 = (float*)d_out;
    float* o2 = o1 + (size_t)kB * kN * kDM;

    ln_exchange_k<<<512, 256, 0, stream>>>(I1, I2, n1w, n1b, n2w, n2b, s1, s2);
    col_sum_k<<<64, 256, 0, stream>>>(s1, s2, partial);
    se_mlp_k<<<4, 128, 0, stream>>>(partial, sew1, sew2, scl1, scl2);
    scale_cvt_k<<<2048, 256, 0, stream>>>(s1, s2, scl1, scl2, sA[0], sA[1]);
    cvt_all_k<<<3200, 256, 0, stream>>>(in_w[0], w_in[0], xp_w[0], w_xp[0], out_w[0], w_out[0],
                                        in_w[1], w_in[1], xp_w[1], w_xp[1], out_w[1], w_out[1]);
    // in-proj: M=2048, N=2048, K=512; 64x128 wave tiles -> 512 waves/mamba, 1024 total
    gemm_bt2<4, 8, false><<<256, 256, 0, stream>>>(sA[0], sA[1], w_in[0], w_in[1],
                                                   nullptr, nullptr, xz[0], xz[1],
                                                   kB * kN, 2 * kDI, kDM);
    conv_silu_k<<<16384, 256, 0, stream>>>(xz[0], xz[1], conv_w[0], conv_w[1],
                                           conv_b[0], conv_b[1], xcf[0], xcf[1],
                                           xcb[0], xcb[1]);
    gemm_bt2<1, 1, false><<<256, 256, 0, stream>>>(xcb[0], xcb[1], w_xp[0], w_xp[1],
                                                   nullptr, nullptr, xd[0], xd[1],
                                                   kB * kN, 64, kDI);
    dt_softplus_k<<<4096, 256, 0, stream>>>(xd[0], xd[1], dt_w[0], dt_w[1],
                                            dt_b[0], dt_b[1], dts[0], dts[1]);
    scan_p1<<<512, 256, 0, stream>>>(dts[0], dts[1], xcf[0], xcf[1], xd[0], xd[1],
                                     A_log[0], A_log[1], Pbuf, Hbuf);
    scan_p2<<<256, 256, 0, stream>>>(Pbuf, Hbuf, Init);
    scan_p3<<<512, 256, 0, stream>>>(dts[0], dts[1], xcf[0], xcf[1], xz[0], xz[1],
                                     xd[0], xd[1], A_log[0], A_log[1], Dp[0], Dp[1],
                                     Init, yg[0], yg[1]);
    // out-proj: M=2048, N=512, K=1024; 32x64 wave tiles -> 512 waves/mamba, 1024 total
    gemm_bt2<2, 4, true><<<256, 256, 0, stream>>>(yg[0], yg[1], w_out[0], w_out[1],
                                                  I1, I2, o1, o2, kB * kN, kDM, kDI);
}